// Round 4
// baseline (2040.904 us; speedup 1.0000x reference)
//
#include <hip/hip_runtime.h>
#include <hip/hip_bf16.h>

#define NUM_OPS   100000
#define NUM_MACH  512
#define HDIM      128
#define P1        100352            // m2o hist offset (98*1024)
#define NHIST     200704            // 196*1024 combined hist size
#define NBLK      196               // scan blocks (1024 elems each)
#define NPASS     4
#define VTW       (NHIST / NPASS)   // 50176 virtual targets per fill pass

// ---------------- embedding: out[r,h] = sum_f F[r,f]*W[h,f] + b[h] ----------------
__global__ void k_embed(const float* __restrict__ F,
                        const float* __restrict__ W,
                        const float* __restrict__ b,
                        float* __restrict__ out, int M, int FD) {
    int idx = blockIdx.x * blockDim.x + threadIdx.x;
    if (idx >= M * HDIM) return;
    int r = idx >> 7, h = idx & 127;
    const float* f = F + (size_t)r * FD;
    const float* w = W + (size_t)h * FD;
    float s = b[h];
    for (int i = 0; i < FD; ++i) s += f[i] * w[i];
    out[idx] = s;
}

// ---------------- histogram: prec targets, m2o targets, o2m machine targets ----------------
__global__ void k_hist(const int* __restrict__ prec_e, int nprec,
                       const int* __restrict__ comp_e, int ncomp, int M,
                       int* __restrict__ hist, int* __restrict__ mach_hist) {
    __shared__ int mc[NUM_MACH];
    for (int i = threadIdx.x; i < NUM_MACH; i += blockDim.x) mc[i] = 0;
    __syncthreads();
    int total = nprec + ncomp;
    for (int i = blockIdx.x * blockDim.x + threadIdx.x; i < total; i += gridDim.x * blockDim.x) {
        if (i < nprec) {
            atomicAdd(&hist[prec_e[nprec + i]], 1);
        } else {
            int e = i - nprec;
            int t = comp_e[ncomp + e];
            if (t >= M) atomicAdd(&mc[t - M], 1);
            else        atomicAdd(&hist[P1 + t], 1);
        }
    }
    __syncthreads();
    for (int i = threadIdx.x; i < NUM_MACH; i += blockDim.x)
        if (mc[i]) atomicAdd(&mach_hist[i], mc[i]);
}

// ---------------- scan phase 1: per-block sums (1024 ints / block) ----------------
__global__ __launch_bounds__(256) void k_blocksum(const int* __restrict__ hist, int* __restrict__ partial) {
    __shared__ int sh[256];
    int b = blockIdx.x, t = threadIdx.x;
    int4 v = *(const int4*)(hist + b * 1024 + t * 4);
    sh[t] = v.x + v.y + v.z + v.w;
    __syncthreads();
    for (int o = 128; o; o >>= 1) { if (t < o) sh[t] += sh[t + o]; __syncthreads(); }
    if (!t) partial[b] = sh[0];
}

// ---------------- scan phase 2: scan block partials + machine hist (single block) ----------------
__global__ __launch_bounds__(256) void k_scanblock(const int* __restrict__ partial,
                                                   int* __restrict__ block_off,
                                                   const int* __restrict__ mach_hist,
                                                   int* __restrict__ mach_rs,
                                                   int* __restrict__ mach_cur) {
    __shared__ int sh[256];
    int t = threadIdx.x;
    int v = (t < NBLK) ? partial[t] : 0;
    sh[t] = v; __syncthreads();
    for (int o = 1; o < 256; o <<= 1) {
        int x = (t >= o) ? sh[t - o] : 0; __syncthreads();
        sh[t] += x; __syncthreads();
    }
    if (t < NBLK) block_off[t] = sh[t] - v;   // exclusive
    __syncthreads();
    // machine scan (512 counts, 2 per thread)
    int a = mach_hist[2 * t], b = mach_hist[2 * t + 1];
    int pv = a + b;
    sh[t] = pv; __syncthreads();
    for (int o = 1; o < 256; o <<= 1) {
        int x = (t >= o) ? sh[t - o] : 0; __syncthreads();
        sh[t] += x; __syncthreads();
    }
    int excl = sh[t] - pv;
    mach_rs[2 * t] = excl;      mach_rs[2 * t + 1] = excl + a;
    mach_cur[2 * t] = excl;     mach_cur[2 * t + 1] = excl + a;
    if (t == 255) mach_rs[512] = sh[255];
}

// ---------------- scan phase 3: write exclusive row starts + cursors ----------------
__global__ __launch_bounds__(256) void k_scanwrite(const int* __restrict__ hist,
                                                   const int* __restrict__ block_off,
                                                   int* __restrict__ rs, int* __restrict__ cur) {
    __shared__ int sh[256];
    int b = blockIdx.x, t = threadIdx.x;
    int base_i = b * 1024 + t * 4;
    int4 v = *(const int4*)(hist + base_i);
    int tsum = v.x + v.y + v.z + v.w;
    sh[t] = tsum; __syncthreads();
    for (int o = 1; o < 256; o <<= 1) {
        int x = (t >= o) ? sh[t - o] : 0; __syncthreads();
        sh[t] += x; __syncthreads();
    }
    int off = block_off[b] + sh[t] - tsum;
    int4 r; r.x = off; r.y = off + v.x; r.z = off + v.x + v.y; r.w = off + v.x + v.y + v.z;
    *(int4*)(rs + base_i) = r;
    *(int4*)(cur + base_i) = r;
}

// ---------------- bucket fill, window-partitioned (write locality) ----------------
__global__ void k_fill_pass(const int* __restrict__ prec_e, int nprec,
                            const int* __restrict__ comp_e, int ncomp, int M,
                            int* __restrict__ cur, int* __restrict__ mach_cur,
                            int* __restrict__ bucket_all, int* __restrict__ bucket_mach,
                            int vt_lo, int m_lo) {
    int i = blockIdx.x * blockDim.x + threadIdx.x;
    int total = nprec + ncomp;
    if (i >= total) return;
    if (i < nprec) {
        int t = prec_e[nprec + i];
        if ((unsigned)(t - vt_lo) < (unsigned)VTW) {
            int s = prec_e[i];
            bucket_all[atomicAdd(&cur[t], 1)] = s;
        }
    } else {
        int e = i - nprec;
        int t = comp_e[ncomp + e];
        if (t >= M) {                    // o2m edge, machine target
            int m = t - M;
            if ((unsigned)(m - m_lo) < (unsigned)(NUM_MACH / NPASS)) {
                int s = comp_e[e];
                bucket_mach[atomicAdd(&mach_cur[m], 1)] = s;
            }
        } else {                         // m2o edge, op target
            int vt = P1 + t;
            if ((unsigned)(vt - vt_lo) < (unsigned)VTW) {
                int s = comp_e[e] - M;
                bucket_all[atomicAdd(&cur[vt], 1)] = s;
            }
        }
    }
}

// ---------------- fused dual GEMM: Y[m,0:128]=X@Wa^T+ba (by=0), Y[m,128:256]=X@Wb^T+bb (by=1) ----------------
#define BM 128
#define BN 128
#define BK 16
__global__ __launch_bounds__(256) void k_gemm_dual(
    const float* __restrict__ X, int M,
    const float* __restrict__ Wa, const float* __restrict__ ba,
    const float* __restrict__ Wb, const float* __restrict__ bb,
    float* __restrict__ Y) {
    __shared__ float As[BK][BM + 4];
    __shared__ float Bs[BK][BN + 4];
    int by = blockIdx.y;
    int m0 = blockIdx.x * BM;
    const float* W    = by ? Wb : Wa;
    const float* bias = by ? bb : ba;
    int colbase = by * 128;

    int t  = threadIdx.x;
    int tx = t & 15, ty = t >> 4;
    int lr = t >> 1;           // load row 0..127
    int lk = (t & 1) * 8;      // load k-offset {0,8}
    float acc[8][8] = {};

    for (int k0 = 0; k0 < HDIM; k0 += BK) {
        int gm = m0 + lr;
        float4 a0 = make_float4(0.f, 0.f, 0.f, 0.f), a1 = a0;
        if (gm < M) {
            a0 = *(const float4*)(X + (size_t)gm * HDIM + k0 + lk);
            a1 = *(const float4*)(X + (size_t)gm * HDIM + k0 + lk + 4);
        }
        float4 b0 = *(const float4*)(W + (size_t)lr * HDIM + k0 + lk);
        float4 b1 = *(const float4*)(W + (size_t)lr * HDIM + k0 + lk + 4);
        As[lk + 0][lr] = a0.x; As[lk + 1][lr] = a0.y; As[lk + 2][lr] = a0.z; As[lk + 3][lr] = a0.w;
        As[lk + 4][lr] = a1.x; As[lk + 5][lr] = a1.y; As[lk + 6][lr] = a1.z; As[lk + 7][lr] = a1.w;
        Bs[lk + 0][lr] = b0.x; Bs[lk + 1][lr] = b0.y; Bs[lk + 2][lr] = b0.z; Bs[lk + 3][lr] = b0.w;
        Bs[lk + 4][lr] = b1.x; Bs[lk + 5][lr] = b1.y; Bs[lk + 6][lr] = b1.z; Bs[lk + 7][lr] = b1.w;
        __syncthreads();
#pragma unroll
        for (int kk = 0; kk < BK; ++kk) {
            float4 xa0 = *(const float4*)&As[kk][ty * 8];
            float4 xa1 = *(const float4*)&As[kk][ty * 8 + 4];
            float4 xb0 = *(const float4*)&Bs[kk][tx * 8];
            float4 xb1 = *(const float4*)&Bs[kk][tx * 8 + 4];
            float av[8] = {xa0.x, xa0.y, xa0.z, xa0.w, xa1.x, xa1.y, xa1.z, xa1.w};
            float bv[8] = {xb0.x, xb0.y, xb0.z, xb0.w, xb1.x, xb1.y, xb1.z, xb1.w};
#pragma unroll
            for (int i = 0; i < 8; ++i)
#pragma unroll
                for (int j = 0; j < 8; ++j)
                    acc[i][j] += av[i] * bv[j];
        }
        __syncthreads();
    }
    float bv[8];
#pragma unroll
    for (int j = 0; j < 8; ++j) bv[j] = bias[tx * 8 + j];
#pragma unroll
    for (int i = 0; i < 8; ++i) {
        int gm = m0 + ty * 8 + i;
        if (gm < M) {
            float4 o0 = make_float4(acc[i][0] + bv[0], acc[i][1] + bv[1], acc[i][2] + bv[2], acc[i][3] + bv[3]);
            float4 o1 = make_float4(acc[i][4] + bv[4], acc[i][5] + bv[5], acc[i][6] + bv[6], acc[i][7] + bv[7]);
            float* dst = Y + (size_t)gm * 256 + colbase + tx * 8;
            *(float4*)dst = o0;
            *(float4*)(dst + 4) = o1;
        }
    }
}

// ---------------- machine linear: Y = X @ W^T + b ----------------
__global__ __launch_bounds__(128) void k_mach_linear(
    const float* __restrict__ X, const float* __restrict__ W,
    const float* __restrict__ b, float* __restrict__ Y) {
    __shared__ float row[HDIM];
    int r = blockIdx.x, t = threadIdx.x;
    row[t] = X[(size_t)r * HDIM + t];
    __syncthreads();
    const float* w = W + (size_t)t * HDIM;
    float s = b[t];
#pragma unroll 8
    for (int k = 0; k < HDIM; ++k) s += row[k] * w[k];
    Y[(size_t)r * HDIM + t] = s;
}

// ---------------- fused op update: gather prec + gather m2o + emb + LN ----------------
__global__ __launch_bounds__(256) void k_op_fused(
    const float* __restrict__ op_emb, const float* __restrict__ op_tc,
    const float* __restrict__ mach_c,
    const int* __restrict__ rs, const int* __restrict__ bucket_all,
    const float* __restrict__ g, const float* __restrict__ bt,
    float* __restrict__ dst, int M) {
    int wave = threadIdx.x >> 6, lane = threadIdx.x & 63;
    int r = blockIdx.x * 4 + wave;
    if (r >= M) return;
    int h = lane * 2;

    float a0 = 0.f, a1 = 0.f;
    int s0 = rs[r], e0 = rs[r + 1];
    for (int j = s0; j < e0; ++j) {
        int s = __builtin_amdgcn_readfirstlane(bucket_all[j]);
        float2 v = *(const float2*)(op_tc + (size_t)s * 256 + h);
        a0 += v.x; a1 += v.y;
    }
    float pinv = 1.f / fmaxf((float)(e0 - s0), 1.f);

    float b0 = 0.f, b1 = 0.f;
    int s1 = rs[P1 + r], e1 = rs[P1 + r + 1];
    for (int j = s1; j < e1; ++j) {
        int m = __builtin_amdgcn_readfirstlane(bucket_all[j]);
        float2 v = *(const float2*)(mach_c + m * HDIM + h);
        b0 += v.x; b1 += v.y;
    }
    float cinv = 1.f / fmaxf((float)(e1 - s1), 1.f);

    float2 e = *(const float2*)(op_emb + (size_t)r * HDIM + h);
    float x0 = e.x + a0 * pinv + b0 * cinv;
    float x1 = e.y + a1 * pinv + b1 * cinv;

    float s = x0 + x1;
#pragma unroll
    for (int o = 32; o; o >>= 1) s += __shfl_xor(s, o);
    float mu = s * (1.f / 128.f);
    float d0 = x0 - mu, d1 = x1 - mu;
    float v2 = d0 * d0 + d1 * d1;
#pragma unroll
    for (int o = 32; o; o >>= 1) v2 += __shfl_xor(v2, o);
    float inv = rsqrtf(v2 * (1.f / 128.f) + 1e-5f);
    float2 gg = *(const float2*)(g + h);
    float2 bb = *(const float2*)(bt + h);
    float2 out = make_float2(d0 * inv * gg.x + bb.x, d1 * inv * gg.y + bb.y);
    *(float2*)(dst + (size_t)r * HDIM + h) = out;
}

// ---------------- machine gather: partial sums per (machine, slice) ----------------
__global__ __launch_bounds__(256) void k_mach_gather(
    const int* __restrict__ mach_rs, const int* __restrict__ bucket_mach,
    const float* __restrict__ op_tc, float* __restrict__ mach_sum) {
    int m = blockIdx.x;
    int h = threadIdx.x & 127;
    int slot = threadIdx.x >> 7;   // 0..1
    int slice = blockIdx.y;        // 0..7
    int s0 = mach_rs[m], e0 = mach_rs[m + 1];
    float acc = 0.f;
    for (int j = s0 + slice * 2 + slot; j < e0; j += 16) {
        int s = __builtin_amdgcn_readfirstlane(bucket_mach[j]);
        acc += op_tc[(size_t)s * 256 + 128 + h];
    }
    if (acc != 0.f) atomicAdd(&mach_sum[m * HDIM + h], acc);
}

// ---------------- machine finalize: mean + emb + LN ----------------
__global__ __launch_bounds__(256) void k_mach_fin(
    const float* __restrict__ mach_emb, const float* __restrict__ mach_sum,
    const int* __restrict__ mach_rs,
    const float* __restrict__ g, const float* __restrict__ bt,
    float* __restrict__ dst) {
    int wave = threadIdx.x >> 6, lane = threadIdx.x & 63;
    int m = blockIdx.x * 4 + wave;
    int h = lane * 2;
    float sc = 1.f / fmaxf((float)(mach_rs[m + 1] - mach_rs[m]), 1.f);
    float2 e = *(const float2*)(mach_emb + m * HDIM + h);
    float2 a = *(const float2*)(mach_sum + m * HDIM + h);
    float x0 = e.x + a.x * sc;
    float x1 = e.y + a.y * sc;
    float s = x0 + x1;
#pragma unroll
    for (int o = 32; o; o >>= 1) s += __shfl_xor(s, o);
    float mu = s * (1.f / 128.f);
    float d0 = x0 - mu, d1 = x1 - mu;
    float v2 = d0 * d0 + d1 * d1;
#pragma unroll
    for (int o = 32; o; o >>= 1) v2 += __shfl_xor(v2, o);
    float inv = rsqrtf(v2 * (1.f / 128.f) + 1e-5f);
    float2 gg = *(const float2*)(g + h);
    float2 bb = *(const float2*)(bt + h);
    *(float2*)(dst + m * HDIM + h) =
        make_float2(d0 * inv * gg.x + bb.x, d1 * inv * gg.y + bb.y);
}

extern "C" void kernel_launch(void* const* d_in, const int* in_sizes, int n_in,
                              void* d_out, int out_size, void* d_ws, size_t ws_size,
                              hipStream_t stream) {
    const float* op_feat    = (const float*)d_in[0];
    const float* m_feat     = (const float*)d_in[1];
    const int*   prec_e     = (const int*)d_in[2];
    const int*   comp_e     = (const int*)d_in[3];
    const float* op_emb_W   = (const float*)d_in[4];
    const float* op_emb_b   = (const float*)d_in[5];
    const float* mach_emb_W = (const float*)d_in[6];
    const float* mach_emb_b = (const float*)d_in[7];
    const float* prec_W     = (const float*)d_in[8];
    const float* prec_b     = (const float*)d_in[9];
    const float* compat_W   = (const float*)d_in[10];
    const float* compat_b   = (const float*)d_in[11];
    const float* op_ln_g    = (const float*)d_in[12];
    const float* op_ln_b    = (const float*)d_in[13];
    const float* mach_ln_g  = (const float*)d_in[14];
    const float* mach_ln_b  = (const float*)d_in[15];
    float* out = (float*)d_out;

    const int M = NUM_OPS, NM = NUM_MACH;
    const int nprec = in_sizes[2] / 2;
    const int ncomp = in_sizes[3] / 2;

    float* ws = (float*)d_ws;
    size_t o = 0;
    float* op_emb   = ws + o; o += (size_t)M * HDIM;   // 12.8M
    float* op_tc    = ws + o; o += (size_t)M * 256;    // 25.6M
    float* mach_emb = ws + o; o += (size_t)NM * HDIM;
    float* mach_c   = ws + o; o += (size_t)NM * HDIM;
    float* mach_sum = ws + o; o += (size_t)NM * HDIM;
    int* ip = (int*)(ws + o);
    size_t io = 0;
    int* hist      = ip + io; io += NHIST;
    int* mach_hist = ip + io; io += 512;       // contiguous with hist for one memset
    int* rs        = ip + io; io += NHIST;
    int* cur       = ip + io; io += NHIST;
    int* mach_rs   = ip + io; io += 520;
    int* mach_cur  = ip + io; io += 512;
    int* partial   = ip + io; io += 256;
    int* block_off = ip + io; io += 256;
    int* bucket_all  = ip + io; io += (size_t)nprec + ncomp;
    int* bucket_mach = ip + io; io += (size_t)ncomp;

    // ---- CSR build ----
    hipMemsetAsync(hist, 0, (size_t)(NHIST + 512) * sizeof(int), stream);
    k_hist<<<1024, 256, 0, stream>>>(prec_e, nprec, comp_e, ncomp, M, hist, mach_hist);
    k_blocksum<<<NBLK, 256, 0, stream>>>(hist, partial);
    k_scanblock<<<1, 256, 0, stream>>>(partial, block_off, mach_hist, mach_rs, mach_cur);
    k_scanwrite<<<NBLK, 256, 0, stream>>>(hist, block_off, rs, cur);
    for (int p = 0; p < NPASS; ++p)
        k_fill_pass<<<(nprec + ncomp + 255) / 256, 256, 0, stream>>>(
            prec_e, nprec, comp_e, ncomp, M, cur, mach_cur, bucket_all, bucket_mach,
            p * VTW, p * (NUM_MACH / NPASS));

    // ---- input embeddings ----
    k_embed<<<(M * HDIM + 255) / 256, 256, 0, stream>>>(op_feat, op_emb_W, op_emb_b, op_emb, M, 6);
    k_embed<<<(NM * HDIM + 255) / 256, 256, 0, stream>>>(m_feat, mach_emb_W, mach_emb_b, mach_emb, NM, 2);

    for (int l = 0; l < 2; ++l) {
        int last = (l == 1);
        hipMemsetAsync(mach_sum, 0, (size_t)NM * HDIM * sizeof(float), stream);

        k_gemm_dual<<<dim3((M + BM - 1) / BM, 2), 256, 0, stream>>>(
            op_emb, M, prec_W + (size_t)l * HDIM * HDIM, prec_b + (size_t)l * HDIM,
            compat_W + (size_t)l * HDIM * HDIM, compat_b + (size_t)l * HDIM, op_tc);
        k_mach_linear<<<NM, 128, 0, stream>>>(
            mach_emb, compat_W + (size_t)l * HDIM * HDIM, compat_b + (size_t)l * HDIM, mach_c);

        k_op_fused<<<(M + 3) / 4, 256, 0, stream>>>(
            op_emb, op_tc, mach_c, rs, bucket_all,
            op_ln_g + (size_t)l * HDIM, op_ln_b + (size_t)l * HDIM,
            last ? out : op_emb, M);

        k_mach_gather<<<dim3(NM, 8), 256, 0, stream>>>(mach_rs, bucket_mach, op_tc, mach_sum);
        k_mach_fin<<<NM / 4, 256, 0, stream>>>(
            mach_emb, mach_sum, mach_rs,
            mach_ln_g + (size_t)l * HDIM, mach_ln_b + (size_t)l * HDIM,
            last ? (out + (size_t)M * HDIM) : mach_emb);
    }
}

// Round 5
// 1334.976 us; speedup vs baseline: 1.5288x; 1.5288x over previous
//
#include <hip/hip_runtime.h>
#include <hip/hip_bf16.h>

#define NUM_OPS   100000
#define NUM_MACH  512
#define HDIM      128
#define P1        100352            // m2o hist offset (98*1024)
#define NHIST     200704            // 196*1024 combined hist size
#define NBLK      196               // scan blocks (1024 elems each)

// ---------------- embedding: out[r,h] = sum_f F[r,f]*W[h,f] + b[h] ----------------
__global__ void k_embed(const float* __restrict__ F,
                        const float* __restrict__ W,
                        const float* __restrict__ b,
                        float* __restrict__ out, int M, int FD) {
    int idx = blockIdx.x * blockDim.x + threadIdx.x;
    if (idx >= M * HDIM) return;
    int r = idx >> 7, h = idx & 127;
    const float* f = F + (size_t)r * FD;
    const float* w = W + (size_t)h * FD;
    float s = b[h];
    for (int i = 0; i < FD; ++i) s += f[i] * w[i];
    out[idx] = s;
}

// ---------------- histogram: prec targets, m2o targets, o2m machine targets ----------------
__global__ void k_hist(const int* __restrict__ prec_e, int nprec,
                       const int* __restrict__ comp_e, int ncomp, int M,
                       int* __restrict__ hist, int* __restrict__ mach_hist) {
    __shared__ int mc[NUM_MACH];
    for (int i = threadIdx.x; i < NUM_MACH; i += blockDim.x) mc[i] = 0;
    __syncthreads();
    int total = nprec + ncomp;
    for (int i = blockIdx.x * blockDim.x + threadIdx.x; i < total; i += gridDim.x * blockDim.x) {
        if (i < nprec) {
            atomicAdd(&hist[prec_e[nprec + i]], 1);
        } else {
            int e = i - nprec;
            int t = comp_e[ncomp + e];
            if (t >= M) atomicAdd(&mc[t - M], 1);
            else        atomicAdd(&hist[P1 + t], 1);
        }
    }
    __syncthreads();
    for (int i = threadIdx.x; i < NUM_MACH; i += blockDim.x)
        if (mc[i]) atomicAdd(&mach_hist[i], mc[i]);
}

// ---------------- scan phase 1: per-block sums (1024 ints / block) ----------------
__global__ __launch_bounds__(256) void k_blocksum(const int* __restrict__ hist, int* __restrict__ partial) {
    __shared__ int sh[256];
    int b = blockIdx.x, t = threadIdx.x;
    int4 v = *(const int4*)(hist + b * 1024 + t * 4);
    sh[t] = v.x + v.y + v.z + v.w;
    __syncthreads();
    for (int o = 128; o; o >>= 1) { if (t < o) sh[t] += sh[t + o]; __syncthreads(); }
    if (!t) partial[b] = sh[0];
}

// ---------------- scan phase 2: scan block partials + machine hist (single block) ----------------
__global__ __launch_bounds__(256) void k_scanblock(const int* __restrict__ partial,
                                                   int* __restrict__ block_off,
                                                   const int* __restrict__ mach_hist,
                                                   int* __restrict__ mach_rs,
                                                   int* __restrict__ mach_cur) {
    __shared__ int sh[256];
    int t = threadIdx.x;
    int v = (t < NBLK) ? partial[t] : 0;
    sh[t] = v; __syncthreads();
    for (int o = 1; o < 256; o <<= 1) {
        int x = (t >= o) ? sh[t - o] : 0; __syncthreads();
        sh[t] += x; __syncthreads();
    }
    if (t < NBLK) block_off[t] = sh[t] - v;   // exclusive
    __syncthreads();
    // machine scan (512 counts, 2 per thread)
    int a = mach_hist[2 * t], b = mach_hist[2 * t + 1];
    int pv = a + b;
    sh[t] = pv; __syncthreads();
    for (int o = 1; o < 256; o <<= 1) {
        int x = (t >= o) ? sh[t - o] : 0; __syncthreads();
        sh[t] += x; __syncthreads();
    }
    int excl = sh[t] - pv;
    mach_rs[2 * t] = excl;      mach_rs[2 * t + 1] = excl + a;
    mach_cur[2 * t] = excl;     mach_cur[2 * t + 1] = excl + a;
    if (t == 255) mach_rs[512] = sh[255];
}

// ---------------- scan phase 3: write exclusive row starts + cursors ----------------
__global__ __launch_bounds__(256) void k_scanwrite(const int* __restrict__ hist,
                                                   const int* __restrict__ block_off,
                                                   int* __restrict__ rs, int* __restrict__ cur) {
    __shared__ int sh[256];
    int b = blockIdx.x, t = threadIdx.x;
    int base_i = b * 1024 + t * 4;
    int4 v = *(const int4*)(hist + base_i);
    int tsum = v.x + v.y + v.z + v.w;
    sh[t] = tsum; __syncthreads();
    for (int o = 1; o < 256; o <<= 1) {
        int x = (t >= o) ? sh[t - o] : 0; __syncthreads();
        sh[t] += x; __syncthreads();
    }
    int off = block_off[b] + sh[t] - tsum;
    int4 r; r.x = off; r.y = off + v.x; r.z = off + v.x + v.y; r.w = off + v.x + v.y + v.z;
    *(int4*)(rs + base_i) = r;
    *(int4*)(cur + base_i) = r;
}

// ---------------- bucket fill (single pass — R3 config; partitioning regressed, see R4) ----------------
__global__ void k_fill(const int* __restrict__ prec_e, int nprec,
                       const int* __restrict__ comp_e, int ncomp, int M,
                       int* __restrict__ cur, int* __restrict__ mach_cur,
                       int* __restrict__ bucket_all, int* __restrict__ bucket_mach) {
    int i = blockIdx.x * blockDim.x + threadIdx.x;
    int total = nprec + ncomp;
    if (i >= total) return;
    if (i < nprec) {
        int s = prec_e[i], t = prec_e[nprec + i];
        bucket_all[atomicAdd(&cur[t], 1)] = s;
    } else {
        int e = i - nprec;
        int s = comp_e[e], t = comp_e[ncomp + e];
        if (t >= M) bucket_mach[atomicAdd(&mach_cur[t - M], 1)] = s;
        else        bucket_all[atomicAdd(&cur[P1 + t], 1)] = s - M;
    }
}

// ---------------- op aggregation: P_agg = mean op_emb[prec_src], C_agg = mean mach_emb[m2o_src] ----------------
__global__ __launch_bounds__(256) void k_agg_op(
    const float* __restrict__ op_emb, const float* __restrict__ mach_emb,
    const int* __restrict__ rs, const int* __restrict__ bucket_all,
    float* __restrict__ A, int* __restrict__ flags, int M) {
    int wave = threadIdx.x >> 6, lane = threadIdx.x & 63;
    int r = blockIdx.x * 4 + wave;
    if (r >= M) return;
    int h = lane * 2;

    float a0 = 0.f, a1 = 0.f;
    int s0 = rs[r], e0 = rs[r + 1];
    for (int j = s0; j < e0; ++j) {
        int s = __builtin_amdgcn_readfirstlane(bucket_all[j]);
        float2 v = *(const float2*)(op_emb + (size_t)s * HDIM + h);
        a0 += v.x; a1 += v.y;
    }
    float pinv = 1.f / fmaxf((float)(e0 - s0), 1.f);

    float b0 = 0.f, b1 = 0.f;
    int s1 = rs[P1 + r], e1 = rs[P1 + r + 1];
    for (int j = s1; j < e1; ++j) {
        int m = __builtin_amdgcn_readfirstlane(bucket_all[j]);
        float2 v = *(const float2*)(mach_emb + m * HDIM + h);
        b0 += v.x; b1 += v.y;
    }
    float cinv = 1.f / fmaxf((float)(e1 - s1), 1.f);

    *(float2*)(A + (size_t)r * 256 + h)       = make_float2(a0 * pinv, a1 * pinv);
    *(float2*)(A + (size_t)r * 256 + 128 + h) = make_float2(b0 * cinv, b1 * cinv);
    if (lane == 0) flags[r] = (e0 > s0 ? 1 : 0) | (e1 > s1 ? 2 : 0);
}

// ---------------- fused GEMM + residual + bias-flags + LayerNorm ----------------
// out[r] = LN(op_emb[r] + A[r,0:128]@Wp^T + A[r,128:256]@Wc^T + fp*bp + fc*bc)
#define BM 128
#define BK 16
__global__ __launch_bounds__(256) void k_gemm_ln(
    const float* __restrict__ A, const float* __restrict__ emb,
    const float* __restrict__ Wp, const float* __restrict__ bp,
    const float* __restrict__ Wc, const float* __restrict__ bc,
    const int* __restrict__ flags,
    const float* __restrict__ g, const float* __restrict__ bt,
    float* __restrict__ dst, int M) {
    __shared__ float As[BK][BM + 4];
    __shared__ float Bs[BK][BM + 4];
    __shared__ float redS[BM][17];
    __shared__ float redQ[BM][17];
    __shared__ float mv[BM][2];
    int m0 = blockIdx.x * BM;
    int t = threadIdx.x;
    int tx = t & 15, ty = t >> 4;
    int lr = t >> 1, lk = (t & 1) * 8;
    float acc[8][8] = {};

    for (int k0 = 0; k0 < 256; k0 += BK) {
        const float* W = (k0 < 128) ? Wp : Wc;
        int koff = (k0 < 128) ? k0 : k0 - 128;
        int gm = m0 + lr;
        float4 a0 = make_float4(0.f, 0.f, 0.f, 0.f), a1 = a0;
        if (gm < M) {
            a0 = *(const float4*)(A + (size_t)gm * 256 + k0 + lk);
            a1 = *(const float4*)(A + (size_t)gm * 256 + k0 + lk + 4);
        }
        float4 b0 = *(const float4*)(W + (size_t)lr * HDIM + koff + lk);
        float4 b1 = *(const float4*)(W + (size_t)lr * HDIM + koff + lk + 4);
        As[lk + 0][lr] = a0.x; As[lk + 1][lr] = a0.y; As[lk + 2][lr] = a0.z; As[lk + 3][lr] = a0.w;
        As[lk + 4][lr] = a1.x; As[lk + 5][lr] = a1.y; As[lk + 6][lr] = a1.z; As[lk + 7][lr] = a1.w;
        Bs[lk + 0][lr] = b0.x; Bs[lk + 1][lr] = b0.y; Bs[lk + 2][lr] = b0.z; Bs[lk + 3][lr] = b0.w;
        Bs[lk + 4][lr] = b1.x; Bs[lk + 5][lr] = b1.y; Bs[lk + 6][lr] = b1.z; Bs[lk + 7][lr] = b1.w;
        __syncthreads();
#pragma unroll
        for (int kk = 0; kk < BK; ++kk) {
            float4 xa0 = *(const float4*)&As[kk][ty * 8];
            float4 xa1 = *(const float4*)&As[kk][ty * 8 + 4];
            float4 xb0 = *(const float4*)&Bs[kk][tx * 8];
            float4 xb1 = *(const float4*)&Bs[kk][tx * 8 + 4];
            float av[8] = {xa0.x, xa0.y, xa0.z, xa0.w, xa1.x, xa1.y, xa1.z, xa1.w};
            float bv[8] = {xb0.x, xb0.y, xb0.z, xb0.w, xb1.x, xb1.y, xb1.z, xb1.w};
#pragma unroll
            for (int i = 0; i < 8; ++i)
#pragma unroll
                for (int j = 0; j < 8; ++j)
                    acc[i][j] += av[i] * bv[j];
        }
        __syncthreads();
    }

    // epilogue pass 1: x = acc + emb + flagged biases; partial sum/sumsq
    float bpv[8], bcv[8];
#pragma unroll
    for (int j = 0; j < 8; ++j) { bpv[j] = bp[tx * 8 + j]; bcv[j] = bc[tx * 8 + j]; }
#pragma unroll
    for (int i = 0; i < 8; ++i) {
        int r = m0 + ty * 8 + i;
        if (r < M) {
            float4 e0 = *(const float4*)(emb + (size_t)r * HDIM + tx * 8);
            float4 e1 = *(const float4*)(emb + (size_t)r * HDIM + tx * 8 + 4);
            float es[8] = {e0.x, e0.y, e0.z, e0.w, e1.x, e1.y, e1.z, e1.w};
            int fl = flags[r];
            float fp = (fl & 1) ? 1.f : 0.f, fc = (fl & 2) ? 1.f : 0.f;
            float ps = 0.f, pq = 0.f;
#pragma unroll
            for (int j = 0; j < 8; ++j) {
                float x = acc[i][j] + es[j] + fp * bpv[j] + fc * bcv[j];
                acc[i][j] = x; ps += x; pq += x * x;
            }
            redS[ty * 8 + i][tx] = ps; redQ[ty * 8 + i][tx] = pq;
        }
    }
    __syncthreads();
    if (t < BM) {
        int r = m0 + t;
        if (r < M) {
            float s = 0.f, q = 0.f;
#pragma unroll
            for (int c = 0; c < 16; ++c) { s += redS[t][c]; q += redQ[t][c]; }
            float mu = s * (1.f / 128.f);
            float var = q * (1.f / 128.f) - mu * mu;
            mv[t][0] = mu; mv[t][1] = rsqrtf(fmaxf(var, 0.f) + 1e-5f);
        }
    }
    __syncthreads();
    float gv[8], bv2[8];
#pragma unroll
    for (int j = 0; j < 8; ++j) { gv[j] = g[tx * 8 + j]; bv2[j] = bt[tx * 8 + j]; }
#pragma unroll
    for (int i = 0; i < 8; ++i) {
        int r = m0 + ty * 8 + i;
        if (r < M) {
            float mu = mv[ty * 8 + i][0], rstd = mv[ty * 8 + i][1];
            float4 o0 = make_float4((acc[i][0] - mu) * rstd * gv[0] + bv2[0],
                                    (acc[i][1] - mu) * rstd * gv[1] + bv2[1],
                                    (acc[i][2] - mu) * rstd * gv[2] + bv2[2],
                                    (acc[i][3] - mu) * rstd * gv[3] + bv2[3]);
            float4 o1 = make_float4((acc[i][4] - mu) * rstd * gv[4] + bv2[4],
                                    (acc[i][5] - mu) * rstd * gv[5] + bv2[5],
                                    (acc[i][6] - mu) * rstd * gv[6] + bv2[6],
                                    (acc[i][7] - mu) * rstd * gv[7] + bv2[7]);
            float* d = dst + (size_t)r * HDIM + tx * 8;
            *(float4*)d = o0;
            *(float4*)(d + 4) = o1;
        }
    }
}

// ---------------- machine gather: sum op_emb[src] per (machine, slice) ----------------
__global__ __launch_bounds__(256) void k_mach_gather(
    const int* __restrict__ mach_rs, const int* __restrict__ bucket_mach,
    const float* __restrict__ op_emb, float* __restrict__ mach_sum) {
    int m = blockIdx.x;
    int h = threadIdx.x & 127;
    int slot = threadIdx.x >> 7;   // 0..1
    int slice = blockIdx.y;        // 0..7
    int s0 = mach_rs[m], e0 = mach_rs[m + 1];
    float acc = 0.f;
    for (int j = s0 + slice * 2 + slot; j < e0; j += 16) {
        int s = __builtin_amdgcn_readfirstlane(bucket_mach[j]);
        acc += op_emb[(size_t)s * HDIM + h];
    }
    if (acc != 0.f) atomicAdd(&mach_sum[m * HDIM + h], acc);
}

// ---------------- machine update: mean -> @Wc^T + bc -> +emb -> LN ----------------
__global__ __launch_bounds__(128) void k_mach_update(
    const float* __restrict__ mach_emb, const float* __restrict__ mach_sum,
    const int* __restrict__ mach_rs,
    const float* __restrict__ Wc, const float* __restrict__ bc,
    const float* __restrict__ g, const float* __restrict__ bt,
    float* __restrict__ dst) {
    __shared__ float row[HDIM];
    __shared__ float red[4];
    int m = blockIdx.x, t = threadIdx.x;
    int cnt = mach_rs[m + 1] - mach_rs[m];
    float sc = (cnt > 0) ? 1.f / (float)cnt : 0.f;
    row[t] = mach_sum[m * HDIM + t] * sc;
    __syncthreads();
    float dot = bc[t];
    const float* w = Wc + (size_t)t * HDIM;
#pragma unroll 8
    for (int k = 0; k < HDIM; ++k) dot += row[k] * w[k];
    float x = mach_emb[m * HDIM + t] + ((cnt > 0) ? dot : 0.f);
    float s = x, q = x * x;
#pragma unroll
    for (int o = 32; o; o >>= 1) { s += __shfl_xor(s, o); q += __shfl_xor(q, o); }
    int wv = t >> 6;
    if ((t & 63) == 0) { red[wv * 2] = s; red[wv * 2 + 1] = q; }
    __syncthreads();
    s = red[0] + red[2]; q = red[1] + red[3];
    float mu = s * (1.f / 128.f);
    float rstd = rsqrtf(fmaxf(q * (1.f / 128.f) - mu * mu, 0.f) + 1e-5f);
    dst[m * HDIM + t] = (x - mu) * rstd * g[t] + bt[t];
}

extern "C" void kernel_launch(void* const* d_in, const int* in_sizes, int n_in,
                              void* d_out, int out_size, void* d_ws, size_t ws_size,
                              hipStream_t stream) {
    const float* op_feat    = (const float*)d_in[0];
    const float* m_feat     = (const float*)d_in[1];
    const int*   prec_e     = (const int*)d_in[2];
    const int*   comp_e     = (const int*)d_in[3];
    const float* op_emb_W   = (const float*)d_in[4];
    const float* op_emb_b   = (const float*)d_in[5];
    const float* mach_emb_W = (const float*)d_in[6];
    const float* mach_emb_b = (const float*)d_in[7];
    const float* prec_W     = (const float*)d_in[8];
    const float* prec_b     = (const float*)d_in[9];
    const float* compat_W   = (const float*)d_in[10];
    const float* compat_b   = (const float*)d_in[11];
    const float* op_ln_g    = (const float*)d_in[12];
    const float* op_ln_b    = (const float*)d_in[13];
    const float* mach_ln_g  = (const float*)d_in[14];
    const float* mach_ln_b  = (const float*)d_in[15];
    float* out = (float*)d_out;

    const int M = NUM_OPS, NM = NUM_MACH;
    const int nprec = in_sizes[2] / 2;
    const int ncomp = in_sizes[3] / 2;

    float* ws = (float*)d_ws;
    size_t o = 0;
    float* op_emb   = ws + o; o += (size_t)M * HDIM;   // 12.8M
    float* A        = ws + o; o += (size_t)M * 256;    // 25.6M (P_agg || C_agg)
    float* mach_emb = ws + o; o += (size_t)NM * HDIM;
    float* mach_sum = ws + o; o += (size_t)NM * HDIM;
    int* ip = (int*)(ws + o);
    size_t io = 0;
    int* hist      = ip + io; io += NHIST;
    int* mach_hist = ip + io; io += 512;       // contiguous with hist for one memset
    int* rs        = ip + io; io += NHIST;
    int* cur       = ip + io; io += NHIST;
    int* mach_rs   = ip + io; io += 520;
    int* mach_cur  = ip + io; io += 512;
    int* partial   = ip + io; io += 256;
    int* block_off = ip + io; io += 256;
    int* flags     = ip + io; io += M;
    int* bucket_all  = ip + io; io += (size_t)nprec + ncomp;
    int* bucket_mach = ip + io; io += (size_t)ncomp;

    // ---- CSR build ----
    hipMemsetAsync(hist, 0, (size_t)(NHIST + 512) * sizeof(int), stream);
    k_hist<<<1024, 256, 0, stream>>>(prec_e, nprec, comp_e, ncomp, M, hist, mach_hist);
    k_blocksum<<<NBLK, 256, 0, stream>>>(hist, partial);
    k_scanblock<<<1, 256, 0, stream>>>(partial, block_off, mach_hist, mach_rs, mach_cur);
    k_scanwrite<<<NBLK, 256, 0, stream>>>(hist, block_off, rs, cur);
    k_fill<<<(nprec + ncomp + 255) / 256, 256, 0, stream>>>(
        prec_e, nprec, comp_e, ncomp, M, cur, mach_cur, bucket_all, bucket_mach);

    // ---- input embeddings ----
    k_embed<<<(M * HDIM + 255) / 256, 256, 0, stream>>>(op_feat, op_emb_W, op_emb_b, op_emb, M, 6);
    k_embed<<<(NM * HDIM + 255) / 256, 256, 0, stream>>>(m_feat, mach_emb_W, mach_emb_b, mach_emb, NM, 2);

    for (int l = 0; l < 2; ++l) {
        int last = (l == 1);
        const float* Wp = prec_W   + (size_t)l * HDIM * HDIM;
        const float* bp = prec_b   + (size_t)l * HDIM;
        const float* Wc = compat_W + (size_t)l * HDIM * HDIM;
        const float* bc = compat_b + (size_t)l * HDIM;

        hipMemsetAsync(mach_sum, 0, (size_t)NM * HDIM * sizeof(float), stream);

        // both aggregations read OLD op_emb / mach_emb
        k_agg_op<<<(M + 3) / 4, 256, 0, stream>>>(op_emb, mach_emb, rs, bucket_all, A, flags, M);
        k_mach_gather<<<dim3(NM, 8), 256, 0, stream>>>(mach_rs, bucket_mach, op_emb, mach_sum);

        // op update (overwrites op_emb after all reads of it)
        k_gemm_ln<<<(M + BM - 1) / BM, 256, 0, stream>>>(
            A, op_emb, Wp, bp, Wc, bc, flags,
            op_ln_g + (size_t)l * HDIM, op_ln_b + (size_t)l * HDIM,
            last ? out : op_emb, M);

        // machine update (overwrites mach_emb after k_agg_op read it)
        k_mach_update<<<NM, 128, 0, stream>>>(
            mach_emb, mach_sum, mach_rs, Wc, bc,
            mach_ln_g + (size_t)l * HDIM, mach_ln_b + (size_t)l * HDIM,
            last ? (out + (size_t)M * HDIM) : mach_emb);
    }
}

// Round 6
// 1147.316 us; speedup vs baseline: 1.7789x; 1.1636x over previous
//
#include <hip/hip_runtime.h>
#include <hip/hip_bf16.h>

#define NUM_OPS   100000
#define NUM_MACH  512
#define HDIM      128
#define P1        100352            // m2o hist offset (98*1024)
#define NHIST     200704            // 196*1024 combined hist size
#define NBLK      196               // hist scan blocks (1024 elems each)
#define NBM       256               // counting-sort blocks for machine buckets
#define MHWORDS   (NUM_MACH * NBM)  // 131072 = 128*1024
#define NBLK_M    128               // blockhist scan blocks

// ---------------- embedding: out[r,h] = sum_f F[r,f]*W[h,f] + b[h] ----------------
__global__ void k_embed(const float* __restrict__ F,
                        const float* __restrict__ W,
                        const float* __restrict__ b,
                        float* __restrict__ out, int M, int FD) {
    int idx = blockIdx.x * blockDim.x + threadIdx.x;
    if (idx >= M * HDIM) return;
    int r = idx >> 7, h = idx & 127;
    const float* f = F + (size_t)r * FD;
    const float* w = W + (size_t)h * FD;
    float s = b[h];
    for (int i = 0; i < FD; ++i) s += f[i] * w[i];
    out[idx] = s;
}

// ---------------- op-side histogram: prec targets + m2o targets (both op-indexed) ----------------
__global__ void k_hist(const int* __restrict__ prec_e, int nprec,
                       const int* __restrict__ comp_e, int E,
                       int* __restrict__ hist) {
    int i = blockIdx.x * blockDim.x + threadIdx.x;
    if (i >= nprec + E) return;
    if (i < nprec) atomicAdd(&hist[prec_e[nprec + i]], 1);
    else           atomicAdd(&hist[P1 + comp_e[i - nprec]], 1);   // m2o target = op of pair
}

// ---------------- machine counting-sort pass A: per-block LDS histograms ----------------
__global__ __launch_bounds__(256) void k_mhist(const int* __restrict__ comp_e, int E, int M,
                                               int* __restrict__ blockhist) {
    __shared__ int h[NUM_MACH];
    for (int i = threadIdx.x; i < NUM_MACH; i += 256) h[i] = 0;
    __syncthreads();
    int blk = blockIdx.x;
    int ch = (E + NBM - 1) / NBM;
    int e0 = blk * ch, e1 = min(E, e0 + ch);
    for (int e = e0 + threadIdx.x; e < e1; e += 256)
        atomicAdd(&h[comp_e[E + e] - M], 1);          // machine of pair e (LDS atomic)
    __syncthreads();
    for (int i = threadIdx.x; i < NUM_MACH; i += 256)
        blockhist[i * NBM + blk] = h[i];              // bin-major for scan
}

// ---------------- scan phase 1: per-block sums (1024 ints / block) ----------------
__global__ __launch_bounds__(256) void k_blocksum(const int* __restrict__ arr, int* __restrict__ partial) {
    __shared__ int sh[256];
    int b = blockIdx.x, t = threadIdx.x;
    int4 v = *(const int4*)(arr + b * 1024 + t * 4);
    sh[t] = v.x + v.y + v.z + v.w;
    __syncthreads();
    for (int o = 128; o; o >>= 1) { if (t < o) sh[t] += sh[t + o]; __syncthreads(); }
    if (!t) partial[b] = sh[0];
}

// ---------------- scan phase 2: exclusive scan of <=256 partials, single block ----------------
__global__ __launch_bounds__(256) void k_scanpart(const int* __restrict__ partial, int n,
                                                  int* __restrict__ block_off) {
    __shared__ int sh[256];
    int t = threadIdx.x;
    int v = (t < n) ? partial[t] : 0;
    sh[t] = v; __syncthreads();
    for (int o = 1; o < 256; o <<= 1) {
        int x = (t >= o) ? sh[t - o] : 0; __syncthreads();
        sh[t] += x; __syncthreads();
    }
    if (t < n) block_off[t] = sh[t] - v;
}

// ---------------- scan phase 3: write exclusive offsets (+ optional cursor copy) ----------------
__global__ __launch_bounds__(256) void k_scanwrite(const int* __restrict__ arr,
                                                   const int* __restrict__ block_off,
                                                   int* __restrict__ rs, int* __restrict__ cur) {
    __shared__ int sh[256];
    int b = blockIdx.x, t = threadIdx.x;
    int base_i = b * 1024 + t * 4;
    int4 v = *(const int4*)(arr + base_i);
    int tsum = v.x + v.y + v.z + v.w;
    sh[t] = tsum; __syncthreads();
    for (int o = 1; o < 256; o <<= 1) {
        int x = (t >= o) ? sh[t - o] : 0; __syncthreads();
        sh[t] += x; __syncthreads();
    }
    int off = block_off[b] + sh[t] - tsum;
    int4 r; r.x = off; r.y = off + v.x; r.z = off + v.x + v.y; r.w = off + v.x + v.y + v.z;
    *(int4*)(rs + base_i) = r;
    if (cur) *(int4*)(cur + base_i) = r;
}

// ---------------- extract machine row starts from scanned blockhist column 0 ----------------
__global__ void k_machrs(const int* __restrict__ moff, int* __restrict__ mach_rs, int E) {
    int t = threadIdx.x;
    for (int m = t; m < NUM_MACH; m += 256) mach_rs[m] = moff[m * NBM];
    if (t == 0) mach_rs[NUM_MACH] = E;
}

// ---------------- op-side bucket fill (atomic cursors; chain ~8) ----------------
__global__ void k_fill_op(const int* __restrict__ prec_e, int nprec,
                          const int* __restrict__ comp_e, int E, int M,
                          int* __restrict__ cur, int* __restrict__ bucket_all) {
    int i = blockIdx.x * blockDim.x + threadIdx.x;
    if (i >= nprec + E) return;
    if (i < nprec) {
        int s = prec_e[i], t = prec_e[nprec + i];
        bucket_all[atomicAdd(&cur[t], 1)] = s;
    } else {
        int e = i - nprec;
        int opi = comp_e[e];
        int m = comp_e[E + e] - M;
        bucket_all[atomicAdd(&cur[P1 + opi], 1)] = m;   // store machine index
    }
}

// ---------------- machine counting-sort pass B: placement via LDS cursors ----------------
__global__ __launch_bounds__(256) void k_fill_mach(const int* __restrict__ comp_e, int E, int M,
                                                   const int* __restrict__ moff,
                                                   int* __restrict__ bucket_mach) {
    __shared__ int cur[NUM_MACH];
    int blk = blockIdx.x;
    for (int i = threadIdx.x; i < NUM_MACH; i += 256) cur[i] = moff[i * NBM + blk];
    __syncthreads();
    int ch = (E + NBM - 1) / NBM;
    int e0 = blk * ch, e1 = min(E, e0 + ch);
    for (int e = e0 + threadIdx.x; e < e1; e += 256) {
        int m = comp_e[E + e] - M;
        int op = comp_e[e];
        int pos = atomicAdd(&cur[m], 1);               // LDS atomic, chain ~6
        bucket_mach[pos] = op;
    }
}

// ---------------- op aggregation: P_agg = mean op_emb[prec_src], C_agg = mean mach_emb[m2o_src] ----------------
__global__ __launch_bounds__(256) void k_agg_op(
    const float* __restrict__ op_emb, const float* __restrict__ mach_emb,
    const int* __restrict__ rs, const int* __restrict__ bucket_all,
    float* __restrict__ A, int* __restrict__ flags, int M) {
    int wave = threadIdx.x >> 6, lane = threadIdx.x & 63;
    int r = blockIdx.x * 4 + wave;
    if (r >= M) return;
    int h = lane * 2;

    float a0 = 0.f, a1 = 0.f;
    int s0 = rs[r], e0 = rs[r + 1];
    for (int j = s0; j < e0; ++j) {
        int s = __builtin_amdgcn_readfirstlane(bucket_all[j]);
        float2 v = *(const float2*)(op_emb + (size_t)s * HDIM + h);
        a0 += v.x; a1 += v.y;
    }
    float pinv = 1.f / fmaxf((float)(e0 - s0), 1.f);

    float b0 = 0.f, b1 = 0.f;
    int s1 = rs[P1 + r], e1 = rs[P1 + r + 1];
    for (int j = s1; j < e1; ++j) {
        int m = __builtin_amdgcn_readfirstlane(bucket_all[j]);
        float2 v = *(const float2*)(mach_emb + m * HDIM + h);
        b0 += v.x; b1 += v.y;
    }
    float cinv = 1.f / fmaxf((float)(e1 - s1), 1.f);

    *(float2*)(A + (size_t)r * 256 + h)       = make_float2(a0 * pinv, a1 * pinv);
    *(float2*)(A + (size_t)r * 256 + 128 + h) = make_float2(b0 * cinv, b1 * cinv);
    if (lane == 0) flags[r] = (e0 > s0 ? 1 : 0) | (e1 > s1 ? 2 : 0);
}

// ---------------- fused GEMM + residual + bias-flags + LayerNorm ----------------
#define BM 128
#define BK 16
__global__ __launch_bounds__(256) void k_gemm_ln(
    const float* __restrict__ A, const float* __restrict__ emb,
    const float* __restrict__ Wp, const float* __restrict__ bp,
    const float* __restrict__ Wc, const float* __restrict__ bc,
    const int* __restrict__ flags,
    const float* __restrict__ g, const float* __restrict__ bt,
    float* __restrict__ dst, int M) {
    __shared__ float As[BK][BM + 4];
    __shared__ float Bs[BK][BM + 4];
    __shared__ float redS[BM][17];
    __shared__ float redQ[BM][17];
    __shared__ float mv[BM][2];
    int m0 = blockIdx.x * BM;
    int t = threadIdx.x;
    int tx = t & 15, ty = t >> 4;
    int lr = t >> 1, lk = (t & 1) * 8;
    float acc[8][8] = {};

    for (int k0 = 0; k0 < 256; k0 += BK) {
        const float* W = (k0 < 128) ? Wp : Wc;
        int koff = (k0 < 128) ? k0 : k0 - 128;
        int gm = m0 + lr;
        float4 a0 = make_float4(0.f, 0.f, 0.f, 0.f), a1 = a0;
        if (gm < M) {
            a0 = *(const float4*)(A + (size_t)gm * 256 + k0 + lk);
            a1 = *(const float4*)(A + (size_t)gm * 256 + k0 + lk + 4);
        }
        float4 b0 = *(const float4*)(W + (size_t)lr * HDIM + koff + lk);
        float4 b1 = *(const float4*)(W + (size_t)lr * HDIM + koff + lk + 4);
        As[lk + 0][lr] = a0.x; As[lk + 1][lr] = a0.y; As[lk + 2][lr] = a0.z; As[lk + 3][lr] = a0.w;
        As[lk + 4][lr] = a1.x; As[lk + 5][lr] = a1.y; As[lk + 6][lr] = a1.z; As[lk + 7][lr] = a1.w;
        Bs[lk + 0][lr] = b0.x; Bs[lk + 1][lr] = b0.y; Bs[lk + 2][lr] = b0.z; Bs[lk + 3][lr] = b0.w;
        Bs[lk + 4][lr] = b1.x; Bs[lk + 5][lr] = b1.y; Bs[lk + 6][lr] = b1.z; Bs[lk + 7][lr] = b1.w;
        __syncthreads();
#pragma unroll
        for (int kk = 0; kk < BK; ++kk) {
            float4 xa0 = *(const float4*)&As[kk][ty * 8];
            float4 xa1 = *(const float4*)&As[kk][ty * 8 + 4];
            float4 xb0 = *(const float4*)&Bs[kk][tx * 8];
            float4 xb1 = *(const float4*)&Bs[kk][tx * 8 + 4];
            float av[8] = {xa0.x, xa0.y, xa0.z, xa0.w, xa1.x, xa1.y, xa1.z, xa1.w};
            float bv[8] = {xb0.x, xb0.y, xb0.z, xb0.w, xb1.x, xb1.y, xb1.z, xb1.w};
#pragma unroll
            for (int i = 0; i < 8; ++i)
#pragma unroll
                for (int j = 0; j < 8; ++j)
                    acc[i][j] += av[i] * bv[j];
        }
        __syncthreads();
    }

    float bpv[8], bcv[8];
#pragma unroll
    for (int j = 0; j < 8; ++j) { bpv[j] = bp[tx * 8 + j]; bcv[j] = bc[tx * 8 + j]; }
#pragma unroll
    for (int i = 0; i < 8; ++i) {
        int r = m0 + ty * 8 + i;
        if (r < M) {
            float4 e0 = *(const float4*)(emb + (size_t)r * HDIM + tx * 8);
            float4 e1 = *(const float4*)(emb + (size_t)r * HDIM + tx * 8 + 4);
            float es[8] = {e0.x, e0.y, e0.z, e0.w, e1.x, e1.y, e1.z, e1.w};
            int fl = flags[r];
            float fp = (fl & 1) ? 1.f : 0.f, fc = (fl & 2) ? 1.f : 0.f;
            float ps = 0.f, pq = 0.f;
#pragma unroll
            for (int j = 0; j < 8; ++j) {
                float x = acc[i][j] + es[j] + fp * bpv[j] + fc * bcv[j];
                acc[i][j] = x; ps += x; pq += x * x;
            }
            redS[ty * 8 + i][tx] = ps; redQ[ty * 8 + i][tx] = pq;
        }
    }
    __syncthreads();
    if (t < BM) {
        int r = m0 + t;
        if (r < M) {
            float s = 0.f, q = 0.f;
#pragma unroll
            for (int c = 0; c < 16; ++c) { s += redS[t][c]; q += redQ[t][c]; }
            float mu = s * (1.f / 128.f);
            float var = q * (1.f / 128.f) - mu * mu;
            mv[t][0] = mu; mv[t][1] = rsqrtf(fmaxf(var, 0.f) + 1e-5f);
        }
    }
    __syncthreads();
    float gv[8], bv2[8];
#pragma unroll
    for (int j = 0; j < 8; ++j) { gv[j] = g[tx * 8 + j]; bv2[j] = bt[tx * 8 + j]; }
#pragma unroll
    for (int i = 0; i < 8; ++i) {
        int r = m0 + ty * 8 + i;
        if (r < M) {
            float mu = mv[ty * 8 + i][0], rstd = mv[ty * 8 + i][1];
            float4 o0 = make_float4((acc[i][0] - mu) * rstd * gv[0] + bv2[0],
                                    (acc[i][1] - mu) * rstd * gv[1] + bv2[1],
                                    (acc[i][2] - mu) * rstd * gv[2] + bv2[2],
                                    (acc[i][3] - mu) * rstd * gv[3] + bv2[3]);
            float4 o1 = make_float4((acc[i][4] - mu) * rstd * gv[4] + bv2[4],
                                    (acc[i][5] - mu) * rstd * gv[5] + bv2[5],
                                    (acc[i][6] - mu) * rstd * gv[6] + bv2[6],
                                    (acc[i][7] - mu) * rstd * gv[7] + bv2[7]);
            float* d = dst + (size_t)r * HDIM + tx * 8;
            *(float4*)d = o0;
            *(float4*)(d + 4) = o1;
        }
    }
}

// ---------------- machine gather: sum op_emb[src] per (machine, slice) ----------------
__global__ __launch_bounds__(256) void k_mach_gather(
    const int* __restrict__ mach_rs, const int* __restrict__ bucket_mach,
    const float* __restrict__ op_emb, float* __restrict__ mach_sum) {
    int m = blockIdx.x;
    int h = threadIdx.x & 127;
    int slot = threadIdx.x >> 7;   // 0..1
    int slice = blockIdx.y;        // 0..7
    int s0 = mach_rs[m], e0 = mach_rs[m + 1];
    float acc = 0.f;
    for (int j = s0 + slice * 2 + slot; j < e0; j += 16) {
        int s = __builtin_amdgcn_readfirstlane(bucket_mach[j]);
        acc += op_emb[(size_t)s * HDIM + h];
    }
    if (acc != 0.f) atomicAdd(&mach_sum[m * HDIM + h], acc);
}

// ---------------- machine update: mean -> @Wc^T + bc -> +emb -> LN ----------------
__global__ __launch_bounds__(128) void k_mach_update(
    const float* __restrict__ mach_emb, const float* __restrict__ mach_sum,
    const int* __restrict__ mach_rs,
    const float* __restrict__ Wc, const float* __restrict__ bc,
    const float* __restrict__ g, const float* __restrict__ bt,
    float* __restrict__ dst) {
    __shared__ float row[HDIM];
    __shared__ float red[4];
    int m = blockIdx.x, t = threadIdx.x;
    int cnt = mach_rs[m + 1] - mach_rs[m];
    float sc = (cnt > 0) ? 1.f / (float)cnt : 0.f;
    row[t] = mach_sum[m * HDIM + t] * sc;
    __syncthreads();
    float dot = bc[t];
    const float* w = Wc + (size_t)t * HDIM;
#pragma unroll 8
    for (int k = 0; k < HDIM; ++k) dot += row[k] * w[k];
    float x = mach_emb[m * HDIM + t] + ((cnt > 0) ? dot : 0.f);
    float s = x, q = x * x;
#pragma unroll
    for (int o = 32; o; o >>= 1) { s += __shfl_xor(s, o); q += __shfl_xor(q, o); }
    int wv = t >> 6;
    if ((t & 63) == 0) { red[wv * 2] = s; red[wv * 2 + 1] = q; }
    __syncthreads();
    s = red[0] + red[2]; q = red[1] + red[3];
    float mu = s * (1.f / 128.f);
    float rstd = rsqrtf(fmaxf(q * (1.f / 128.f) - mu * mu, 0.f) + 1e-5f);
    dst[m * HDIM + t] = (x - mu) * rstd * g[t] + bt[t];
}

extern "C" void kernel_launch(void* const* d_in, const int* in_sizes, int n_in,
                              void* d_out, int out_size, void* d_ws, size_t ws_size,
                              hipStream_t stream) {
    const float* op_feat    = (const float*)d_in[0];
    const float* m_feat     = (const float*)d_in[1];
    const int*   prec_e     = (const int*)d_in[2];
    const int*   comp_e     = (const int*)d_in[3];
    const float* op_emb_W   = (const float*)d_in[4];
    const float* op_emb_b   = (const float*)d_in[5];
    const float* mach_emb_W = (const float*)d_in[6];
    const float* mach_emb_b = (const float*)d_in[7];
    const float* prec_W     = (const float*)d_in[8];
    const float* prec_b     = (const float*)d_in[9];
    const float* compat_W   = (const float*)d_in[10];
    const float* compat_b   = (const float*)d_in[11];
    const float* op_ln_g    = (const float*)d_in[12];
    const float* op_ln_b    = (const float*)d_in[13];
    const float* mach_ln_g  = (const float*)d_in[14];
    const float* mach_ln_b  = (const float*)d_in[15];
    float* out = (float*)d_out;

    const int M = NUM_OPS, NM = NUM_MACH;
    const int nprec = in_sizes[2] / 2;
    const int ncomp = in_sizes[3] / 2;
    const int E = ncomp / 2;   // bidirectional pairs: first half o2m, second half m2o (mirror)

    float* ws = (float*)d_ws;
    size_t o = 0;
    float* op_emb   = ws + o; o += (size_t)M * HDIM;   // 51 MB
    float* A        = ws + o; o += (size_t)M * 256;    // 102 MB (P_agg || C_agg)
    float* mach_emb = ws + o; o += (size_t)NM * HDIM;
    float* mach_sum = ws + o; o += (size_t)NM * HDIM;
    int* ip = (int*)(ws + o);
    size_t io = 0;
    int* hist      = ip + io; io += NHIST;
    int* rs        = ip + io; io += NHIST;
    int* cur       = ip + io; io += NHIST;
    int* blockhist = ip + io; io += MHWORDS;
    int* moff      = ip + io; io += MHWORDS;
    int* mach_rs   = ip + io; io += NM + 8;
    int* partialA  = ip + io; io += 256;
    int* block_offA= ip + io; io += 256;
    int* partialB  = ip + io; io += 256;
    int* block_offB= ip + io; io += 256;
    int* flags     = ip + io; io += M;
    int* bucket_all  = ip + io; io += (size_t)nprec + E;
    int* bucket_mach = ip + io; io += (size_t)E;

    // ---- CSR build ----
    hipMemsetAsync(hist, 0, (size_t)NHIST * sizeof(int), stream);
    k_hist<<<(nprec + E + 255) / 256, 256, 0, stream>>>(prec_e, nprec, comp_e, E, hist);
    k_mhist<<<NBM, 256, 0, stream>>>(comp_e, E, M, blockhist);
    // scan op-side hist (196*1024)
    k_blocksum<<<NBLK, 256, 0, stream>>>(hist, partialA);
    k_scanpart<<<1, 256, 0, stream>>>(partialA, NBLK, block_offA);
    k_scanwrite<<<NBLK, 256, 0, stream>>>(hist, block_offA, rs, cur);
    // scan machine blockhist (128*1024)
    k_blocksum<<<NBLK_M, 256, 0, stream>>>(blockhist, partialB);
    k_scanpart<<<1, 256, 0, stream>>>(partialB, NBLK_M, block_offB);
    k_scanwrite<<<NBLK_M, 256, 0, stream>>>(blockhist, block_offB, moff, nullptr);
    k_machrs<<<1, 256, 0, stream>>>(moff, mach_rs, E);
    // fills
    k_fill_op<<<(nprec + E + 255) / 256, 256, 0, stream>>>(prec_e, nprec, comp_e, E, M, cur, bucket_all);
    k_fill_mach<<<NBM, 256, 0, stream>>>(comp_e, E, M, moff, bucket_mach);

    // ---- input embeddings ----
    k_embed<<<(M * HDIM + 255) / 256, 256, 0, stream>>>(op_feat, op_emb_W, op_emb_b, op_emb, M, 6);
    k_embed<<<(NM * HDIM + 255) / 256, 256, 0, stream>>>(m_feat, mach_emb_W, mach_emb_b, mach_emb, NM, 2);

    for (int l = 0; l < 2; ++l) {
        int last = (l == 1);
        const float* Wp = prec_W   + (size_t)l * HDIM * HDIM;
        const float* bp = prec_b   + (size_t)l * HDIM;
        const float* Wc = compat_W + (size_t)l * HDIM * HDIM;
        const float* bc = compat_b + (size_t)l * HDIM;

        hipMemsetAsync(mach_sum, 0, (size_t)NM * HDIM * sizeof(float), stream);

        // both aggregations read OLD op_emb / mach_emb
        k_agg_op<<<(M + 3) / 4, 256, 0, stream>>>(op_emb, mach_emb, rs, bucket_all, A, flags, M);
        k_mach_gather<<<dim3(NM, 8), 256, 0, stream>>>(mach_rs, bucket_mach, op_emb, mach_sum);

        // op update (overwrites op_emb after all reads of it)
        k_gemm_ln<<<(M + BM - 1) / BM, 256, 0, stream>>>(
            A, op_emb, Wp, bp, Wc, bc, flags,
            op_ln_g + (size_t)l * HDIM, op_ln_b + (size_t)l * HDIM,
            last ? out : op_emb, M);

        // machine update (overwrites mach_emb after k_agg_op read it)
        k_mach_update<<<NM, 128, 0, stream>>>(
            mach_emb, mach_sum, mach_rs, Wc, bc,
            mach_ln_g + (size_t)l * HDIM, mach_ln_b + (size_t)l * HDIM,
            last ? (out + (size_t)M * HDIM) : mach_emb);
    }
}

// Round 7
// 916.272 us; speedup vs baseline: 2.2274x; 1.2522x over previous
//
#include <hip/hip_runtime.h>
#include <hip/hip_bf16.h>

#define NUM_OPS   100000
#define NUM_MACH  512
#define HDIM      128
#define P1        100352            // m2o hist offset (98*1024)
#define NHIST     200704            // 196*1024 combined hist size
#define NBLK      196               // hist scan blocks (1024 elems each)
#define NBM       256               // counting-sort blocks for machine buckets
#define MHWORDS   (NUM_MACH * NBM)  // 131072 = 128*1024
#define NBLK_M    128               // blockhist scan blocks

// ---------------- embedding: out[r,h] = sum_f F[r,f]*W[h,f] + b[h] ----------------
__global__ void k_embed(const float* __restrict__ F,
                        const float* __restrict__ W,
                        const float* __restrict__ b,
                        float* __restrict__ out, int M, int FD) {
    int idx = blockIdx.x * blockDim.x + threadIdx.x;
    if (idx >= M * HDIM) return;
    int r = idx >> 7, h = idx & 127;
    const float* f = F + (size_t)r * FD;
    const float* w = W + (size_t)h * FD;
    float s = b[h];
    for (int i = 0; i < FD; ++i) s += f[i] * w[i];
    out[idx] = s;
}

// ---------------- op-side histogram: prec targets + m2o targets (both op-indexed) ----------------
__global__ void k_hist(const int* __restrict__ prec_e, int nprec,
                       const int* __restrict__ comp_e, int E,
                       int* __restrict__ hist) {
    int i = blockIdx.x * blockDim.x + threadIdx.x;
    if (i >= nprec + E) return;
    if (i < nprec) atomicAdd(&hist[prec_e[nprec + i]], 1);
    else           atomicAdd(&hist[P1 + comp_e[i - nprec]], 1);   // m2o target = op of pair
}

// ---------------- machine counting-sort pass A: per-block LDS histograms ----------------
__global__ __launch_bounds__(256) void k_mhist(const int* __restrict__ comp_e, int E, int M,
                                               int* __restrict__ blockhist) {
    __shared__ int h[NUM_MACH];
    for (int i = threadIdx.x; i < NUM_MACH; i += 256) h[i] = 0;
    __syncthreads();
    int blk = blockIdx.x;
    int ch = (E + NBM - 1) / NBM;
    int e0 = blk * ch, e1 = min(E, e0 + ch);
    for (int e = e0 + threadIdx.x; e < e1; e += 256)
        atomicAdd(&h[comp_e[E + e] - M], 1);          // machine of pair e (LDS atomic)
    __syncthreads();
    for (int i = threadIdx.x; i < NUM_MACH; i += 256)
        blockhist[i * NBM + blk] = h[i];              // bin-major for scan
}

// ---------------- scan phase 1: per-block sums (1024 ints / block) ----------------
__global__ __launch_bounds__(256) void k_blocksum(const int* __restrict__ arr, int* __restrict__ partial) {
    __shared__ int sh[256];
    int b = blockIdx.x, t = threadIdx.x;
    int4 v = *(const int4*)(arr + b * 1024 + t * 4);
    sh[t] = v.x + v.y + v.z + v.w;
    __syncthreads();
    for (int o = 128; o; o >>= 1) { if (t < o) sh[t] += sh[t + o]; __syncthreads(); }
    if (!t) partial[b] = sh[0];
}

// ---------------- scan phase 2: exclusive scan of <=256 partials, single block ----------------
__global__ __launch_bounds__(256) void k_scanpart(const int* __restrict__ partial, int n,
                                                  int* __restrict__ block_off) {
    __shared__ int sh[256];
    int t = threadIdx.x;
    int v = (t < n) ? partial[t] : 0;
    sh[t] = v; __syncthreads();
    for (int o = 1; o < 256; o <<= 1) {
        int x = (t >= o) ? sh[t - o] : 0; __syncthreads();
        sh[t] += x; __syncthreads();
    }
    if (t < n) block_off[t] = sh[t] - v;
}

// ---------------- scan phase 3: write exclusive offsets (+ optional cursor copy) ----------------
__global__ __launch_bounds__(256) void k_scanwrite(const int* __restrict__ arr,
                                                   const int* __restrict__ block_off,
                                                   int* __restrict__ rs, int* __restrict__ cur) {
    __shared__ int sh[256];
    int b = blockIdx.x, t = threadIdx.x;
    int base_i = b * 1024 + t * 4;
    int4 v = *(const int4*)(arr + base_i);
    int tsum = v.x + v.y + v.z + v.w;
    sh[t] = tsum; __syncthreads();
    for (int o = 1; o < 256; o <<= 1) {
        int x = (t >= o) ? sh[t - o] : 0; __syncthreads();
        sh[t] += x; __syncthreads();
    }
    int off = block_off[b] + sh[t] - tsum;
    int4 r; r.x = off; r.y = off + v.x; r.z = off + v.x + v.y; r.w = off + v.x + v.y + v.z;
    *(int4*)(rs + base_i) = r;
    if (cur) *(int4*)(cur + base_i) = r;
}

// ---------------- extract machine row starts from scanned blockhist column 0 ----------------
__global__ void k_machrs(const int* __restrict__ moff, int* __restrict__ mach_rs, int E) {
    int t = threadIdx.x;
    for (int m = t; m < NUM_MACH; m += 256) mach_rs[m] = moff[m * NBM];
    if (t == 0) mach_rs[NUM_MACH] = E;
}

// ---------------- op-side bucket fill (atomic cursors; chain ~8) ----------------
__global__ void k_fill_op(const int* __restrict__ prec_e, int nprec,
                          const int* __restrict__ comp_e, int E, int M,
                          int* __restrict__ cur, int* __restrict__ bucket_all) {
    int i = blockIdx.x * blockDim.x + threadIdx.x;
    if (i >= nprec + E) return;
    if (i < nprec) {
        int s = prec_e[i], t = prec_e[nprec + i];
        bucket_all[atomicAdd(&cur[t], 1)] = s;
    } else {
        int e = i - nprec;
        int opi = comp_e[e];
        int m = comp_e[E + e] - M;
        bucket_all[atomicAdd(&cur[P1 + opi], 1)] = m;   // store machine index
    }
}

// ---------------- machine counting-sort pass B: placement via LDS cursors ----------------
__global__ __launch_bounds__(256) void k_fill_mach(const int* __restrict__ comp_e, int E, int M,
                                                   const int* __restrict__ moff,
                                                   int* __restrict__ bucket_mach) {
    __shared__ int cur[NUM_MACH];
    int blk = blockIdx.x;
    for (int i = threadIdx.x; i < NUM_MACH; i += 256) cur[i] = moff[i * NBM + blk];
    __syncthreads();
    int ch = (E + NBM - 1) / NBM;
    int e0 = blk * ch, e1 = min(E, e0 + ch);
    for (int e = e0 + threadIdx.x; e < e1; e += 256) {
        int m = comp_e[E + e] - M;
        int op = comp_e[e];
        int pos = atomicAdd(&cur[m], 1);               // LDS atomic, chain ~6
        bucket_mach[pos] = op;
    }
}

// ---------------- op aggregation, ILP version: wave preloads 64 indices, 4 gathers in flight ----------------
__global__ __launch_bounds__(256) void k_agg_op(
    const float* __restrict__ op_emb, const float* __restrict__ mach_emb,
    const int* __restrict__ rs, const int* __restrict__ bucket_all,
    float* __restrict__ A, int* __restrict__ flags, int M) {
    int wave = threadIdx.x >> 6, lane = threadIdx.x & 63;
    int r = blockIdx.x * 4 + wave;
    if (r >= M) return;
    int h = lane * 2;

    float a0 = 0.f, a1 = 0.f;
    int s0 = rs[r], e0 = rs[r + 1];
    for (int base = s0; base < e0; base += 64) {
        int cnt = min(64, e0 - base);
        int idx = (lane < cnt) ? bucket_all[base + lane] : 0;
        for (int j = 0; j < cnt; j += 4) {
            int i0 = __shfl(idx, j);
            int i1 = __shfl(idx, j + 1);
            int i2 = __shfl(idx, j + 2);
            int i3 = __shfl(idx, j + 3);
            float2 v0 = *(const float2*)(op_emb + (size_t)i0 * HDIM + h);
            float2 v1 = *(const float2*)(op_emb + (size_t)i1 * HDIM + h);
            float2 v2 = *(const float2*)(op_emb + (size_t)i2 * HDIM + h);
            float2 v3 = *(const float2*)(op_emb + (size_t)i3 * HDIM + h);
            a0 += v0.x; a1 += v0.y;
            if (j + 1 < cnt) { a0 += v1.x; a1 += v1.y; }
            if (j + 2 < cnt) { a0 += v2.x; a1 += v2.y; }
            if (j + 3 < cnt) { a0 += v3.x; a1 += v3.y; }
        }
    }
    float pinv = 1.f / fmaxf((float)(e0 - s0), 1.f);

    float b0 = 0.f, b1 = 0.f;
    int s1 = rs[P1 + r], e1 = rs[P1 + r + 1];
    for (int base = s1; base < e1; base += 64) {
        int cnt = min(64, e1 - base);
        int idx = (lane < cnt) ? bucket_all[base + lane] : 0;
        for (int j = 0; j < cnt; j += 4) {
            int i0 = __shfl(idx, j);
            int i1 = __shfl(idx, j + 1);
            int i2 = __shfl(idx, j + 2);
            int i3 = __shfl(idx, j + 3);
            float2 v0 = *(const float2*)(mach_emb + (size_t)i0 * HDIM + h);
            float2 v1 = *(const float2*)(mach_emb + (size_t)i1 * HDIM + h);
            float2 v2 = *(const float2*)(mach_emb + (size_t)i2 * HDIM + h);
            float2 v3 = *(const float2*)(mach_emb + (size_t)i3 * HDIM + h);
            b0 += v0.x; b1 += v0.y;
            if (j + 1 < cnt) { b0 += v1.x; b1 += v1.y; }
            if (j + 2 < cnt) { b0 += v2.x; b1 += v2.y; }
            if (j + 3 < cnt) { b0 += v3.x; b1 += v3.y; }
        }
    }
    float cinv = 1.f / fmaxf((float)(e1 - s1), 1.f);

    *(float2*)(A + (size_t)r * 256 + h)       = make_float2(a0 * pinv, a1 * pinv);
    *(float2*)(A + (size_t)r * 256 + 128 + h) = make_float2(b0 * cinv, b1 * cinv);
    if (lane == 0) flags[r] = (e0 > s0 ? 1 : 0) | (e1 > s1 ? 2 : 0);
}

// ---------------- fused GEMM + residual + bias-flags + LayerNorm ----------------
#define BM 128
#define BK 16
__global__ __launch_bounds__(256) void k_gemm_ln(
    const float* __restrict__ A, const float* __restrict__ emb,
    const float* __restrict__ Wp, const float* __restrict__ bp,
    const float* __restrict__ Wc, const float* __restrict__ bc,
    const int* __restrict__ flags,
    const float* __restrict__ g, const float* __restrict__ bt,
    float* __restrict__ dst, int M) {
    __shared__ float As[BK][BM + 4];
    __shared__ float Bs[BK][BM + 4];
    __shared__ float redS[BM][17];
    __shared__ float redQ[BM][17];
    __shared__ float mv[BM][2];
    int m0 = blockIdx.x * BM;
    int t = threadIdx.x;
    int tx = t & 15, ty = t >> 4;
    int lr = t >> 1, lk = (t & 1) * 8;
    float acc[8][8] = {};

    for (int k0 = 0; k0 < 256; k0 += BK) {
        const float* W = (k0 < 128) ? Wp : Wc;
        int koff = (k0 < 128) ? k0 : k0 - 128;
        int gm = m0 + lr;
        float4 a0 = make_float4(0.f, 0.f, 0.f, 0.f), a1 = a0;
        if (gm < M) {
            a0 = *(const float4*)(A + (size_t)gm * 256 + k0 + lk);
            a1 = *(const float4*)(A + (size_t)gm * 256 + k0 + lk + 4);
        }
        float4 b0 = *(const float4*)(W + (size_t)lr * HDIM + koff + lk);
        float4 b1 = *(const float4*)(W + (size_t)lr * HDIM + koff + lk + 4);
        As[lk + 0][lr] = a0.x; As[lk + 1][lr] = a0.y; As[lk + 2][lr] = a0.z; As[lk + 3][lr] = a0.w;
        As[lk + 4][lr] = a1.x; As[lk + 5][lr] = a1.y; As[lk + 6][lr] = a1.z; As[lk + 7][lr] = a1.w;
        Bs[lk + 0][lr] = b0.x; Bs[lk + 1][lr] = b0.y; Bs[lk + 2][lr] = b0.z; Bs[lk + 3][lr] = b0.w;
        Bs[lk + 4][lr] = b1.x; Bs[lk + 5][lr] = b1.y; Bs[lk + 6][lr] = b1.z; Bs[lk + 7][lr] = b1.w;
        __syncthreads();
#pragma unroll
        for (int kk = 0; kk < BK; ++kk) {
            float4 xa0 = *(const float4*)&As[kk][ty * 8];
            float4 xa1 = *(const float4*)&As[kk][ty * 8 + 4];
            float4 xb0 = *(const float4*)&Bs[kk][tx * 8];
            float4 xb1 = *(const float4*)&Bs[kk][tx * 8 + 4];
            float av[8] = {xa0.x, xa0.y, xa0.z, xa0.w, xa1.x, xa1.y, xa1.z, xa1.w};
            float bv[8] = {xb0.x, xb0.y, xb0.z, xb0.w, xb1.x, xb1.y, xb1.z, xb1.w};
#pragma unroll
            for (int i = 0; i < 8; ++i)
#pragma unroll
                for (int j = 0; j < 8; ++j)
                    acc[i][j] += av[i] * bv[j];
        }
        __syncthreads();
    }

    float bpv[8], bcv[8];
#pragma unroll
    for (int j = 0; j < 8; ++j) { bpv[j] = bp[tx * 8 + j]; bcv[j] = bc[tx * 8 + j]; }
#pragma unroll
    for (int i = 0; i < 8; ++i) {
        int r = m0 + ty * 8 + i;
        if (r < M) {
            float4 e0 = *(const float4*)(emb + (size_t)r * HDIM + tx * 8);
            float4 e1 = *(const float4*)(emb + (size_t)r * HDIM + tx * 8 + 4);
            float es[8] = {e0.x, e0.y, e0.z, e0.w, e1.x, e1.y, e1.z, e1.w};
            int fl = flags[r];
            float fp = (fl & 1) ? 1.f : 0.f, fc = (fl & 2) ? 1.f : 0.f;
            float ps = 0.f, pq = 0.f;
#pragma unroll
            for (int j = 0; j < 8; ++j) {
                float x = acc[i][j] + es[j] + fp * bpv[j] + fc * bcv[j];
                acc[i][j] = x; ps += x; pq += x * x;
            }
            redS[ty * 8 + i][tx] = ps; redQ[ty * 8 + i][tx] = pq;
        }
    }
    __syncthreads();
    if (t < BM) {
        int r = m0 + t;
        if (r < M) {
            float s = 0.f, q = 0.f;
#pragma unroll
            for (int c = 0; c < 16; ++c) { s += redS[t][c]; q += redQ[t][c]; }
            float mu = s * (1.f / 128.f);
            float var = q * (1.f / 128.f) - mu * mu;
            mv[t][0] = mu; mv[t][1] = rsqrtf(fmaxf(var, 0.f) + 1e-5f);
        }
    }
    __syncthreads();
    float gv[8], bv2[8];
#pragma unroll
    for (int j = 0; j < 8; ++j) { gv[j] = g[tx * 8 + j]; bv2[j] = bt[tx * 8 + j]; }
#pragma unroll
    for (int i = 0; i < 8; ++i) {
        int r = m0 + ty * 8 + i;
        if (r < M) {
            float mu = mv[ty * 8 + i][0], rstd = mv[ty * 8 + i][1];
            float4 o0 = make_float4((acc[i][0] - mu) * rstd * gv[0] + bv2[0],
                                    (acc[i][1] - mu) * rstd * gv[1] + bv2[1],
                                    (acc[i][2] - mu) * rstd * gv[2] + bv2[2],
                                    (acc[i][3] - mu) * rstd * gv[3] + bv2[3]);
            float4 o1 = make_float4((acc[i][4] - mu) * rstd * gv[4] + bv2[4],
                                    (acc[i][5] - mu) * rstd * gv[5] + bv2[5],
                                    (acc[i][6] - mu) * rstd * gv[6] + bv2[6],
                                    (acc[i][7] - mu) * rstd * gv[7] + bv2[7]);
            float* d = dst + (size_t)r * HDIM + tx * 8;
            *(float4*)d = o0;
            *(float4*)(d + 4) = o1;
        }
    }
}

// ---------------- machine gather, ILP version: wave-pair owns 64-edge batch ----------------
__global__ __launch_bounds__(256) void k_mach_gather(
    const int* __restrict__ mach_rs, const int* __restrict__ bucket_mach,
    const float* __restrict__ op_emb, float* __restrict__ mach_sum) {
    int m = blockIdx.x;
    int t = threadIdx.x;
    int wave = t >> 6, lane = t & 63;
    int h = (wave & 1) * 64 + lane;        // wave pair covers h 0..127
    int pair = wave >> 1;                  // 0..1
    int s0 = mach_rs[m], e0 = mach_rs[m + 1];
    float acc = 0.f;
    for (int base = s0 + (blockIdx.y * 2 + pair) * 64; base < e0; base += gridDim.y * 128) {
        int cnt = min(64, e0 - base);
        int idx = (lane < cnt) ? bucket_mach[base + lane] : 0;
        for (int j = 0; j < cnt; j += 4) {
            int i0 = __shfl(idx, j);
            int i1 = __shfl(idx, j + 1);
            int i2 = __shfl(idx, j + 2);
            int i3 = __shfl(idx, j + 3);
            float v0 = op_emb[(size_t)i0 * HDIM + h];
            float v1 = op_emb[(size_t)i1 * HDIM + h];
            float v2 = op_emb[(size_t)i2 * HDIM + h];
            float v3 = op_emb[(size_t)i3 * HDIM + h];
            acc += v0;
            if (j + 1 < cnt) acc += v1;
            if (j + 2 < cnt) acc += v2;
            if (j + 3 < cnt) acc += v3;
        }
    }
    atomicAdd(&mach_sum[m * HDIM + h], acc);
}

// ---------------- machine update: mean -> @Wc^T + bc -> +emb -> LN ----------------
__global__ __launch_bounds__(128) void k_mach_update(
    const float* __restrict__ mach_emb, const float* __restrict__ mach_sum,
    const int* __restrict__ mach_rs,
    const float* __restrict__ Wc, const float* __restrict__ bc,
    const float* __restrict__ g, const float* __restrict__ bt,
    float* __restrict__ dst) {
    __shared__ float row[HDIM];
    __shared__ float red[4];
    int m = blockIdx.x, t = threadIdx.x;
    int cnt = mach_rs[m + 1] - mach_rs[m];
    float sc = (cnt > 0) ? 1.f / (float)cnt : 0.f;
    row[t] = mach_sum[m * HDIM + t] * sc;
    __syncthreads();
    float dot = bc[t];
    const float* w = Wc + (size_t)t * HDIM;
#pragma unroll 8
    for (int k = 0; k < HDIM; ++k) dot += row[k] * w[k];
    float x = mach_emb[m * HDIM + t] + ((cnt > 0) ? dot : 0.f);
    float s = x, q = x * x;
#pragma unroll
    for (int o = 32; o; o >>= 1) { s += __shfl_xor(s, o); q += __shfl_xor(q, o); }
    int wv = t >> 6;
    if ((t & 63) == 0) { red[wv * 2] = s; red[wv * 2 + 1] = q; }
    __syncthreads();
    s = red[0] + red[2]; q = red[1] + red[3];
    float mu = s * (1.f / 128.f);
    float rstd = rsqrtf(fmaxf(q * (1.f / 128.f) - mu * mu, 0.f) + 1e-5f);
    dst[m * HDIM + t] = (x - mu) * rstd * g[t] + bt[t];
}

extern "C" void kernel_launch(void* const* d_in, const int* in_sizes, int n_in,
                              void* d_out, int out_size, void* d_ws, size_t ws_size,
                              hipStream_t stream) {
    const float* op_feat    = (const float*)d_in[0];
    const float* m_feat     = (const float*)d_in[1];
    const int*   prec_e     = (const int*)d_in[2];
    const int*   comp_e     = (const int*)d_in[3];
    const float* op_emb_W   = (const float*)d_in[4];
    const float* op_emb_b   = (const float*)d_in[5];
    const float* mach_emb_W = (const float*)d_in[6];
    const float* mach_emb_b = (const float*)d_in[7];
    const float* prec_W     = (const float*)d_in[8];
    const float* prec_b     = (const float*)d_in[9];
    const float* compat_W   = (const float*)d_in[10];
    const float* compat_b   = (const float*)d_in[11];
    const float* op_ln_g    = (const float*)d_in[12];
    const float* op_ln_b    = (const float*)d_in[13];
    const float* mach_ln_g  = (const float*)d_in[14];
    const float* mach_ln_b  = (const float*)d_in[15];
    float* out = (float*)d_out;

    const int M = NUM_OPS, NM = NUM_MACH;
    const int nprec = in_sizes[2] / 2;
    const int ncomp = in_sizes[3] / 2;
    const int E = ncomp / 2;   // bidirectional pairs: first half o2m, second half m2o (mirror)

    float* ws = (float*)d_ws;
    size_t o = 0;
    float* op_emb   = ws + o; o += (size_t)M * HDIM;   // 51 MB
    float* A        = ws + o; o += (size_t)M * 256;    // 102 MB (P_agg || C_agg)
    float* mach_emb = ws + o; o += (size_t)NM * HDIM;
    float* mach_sum = ws + o; o += (size_t)NM * HDIM;
    int* ip = (int*)(ws + o);
    size_t io = 0;
    int* hist      = ip + io; io += NHIST;
    int* rs        = ip + io; io += NHIST;
    int* cur       = ip + io; io += NHIST;
    int* blockhist = ip + io; io += MHWORDS;
    int* moff      = ip + io; io += MHWORDS;
    int* mach_rs   = ip + io; io += NM + 8;
    int* partialA  = ip + io; io += 256;
    int* block_offA= ip + io; io += 256;
    int* partialB  = ip + io; io += 256;
    int* block_offB= ip + io; io += 256;
    int* flags     = ip + io; io += M;
    int* bucket_all  = ip + io; io += (size_t)nprec + E;
    int* bucket_mach = ip + io; io += (size_t)E;

    // ---- CSR build ----
    hipMemsetAsync(hist, 0, (size_t)NHIST * sizeof(int), stream);
    k_hist<<<(nprec + E + 255) / 256, 256, 0, stream>>>(prec_e, nprec, comp_e, E, hist);
    k_mhist<<<NBM, 256, 0, stream>>>(comp_e, E, M, blockhist);
    // scan op-side hist (196*1024)
    k_blocksum<<<NBLK, 256, 0, stream>>>(hist, partialA);
    k_scanpart<<<1, 256, 0, stream>>>(partialA, NBLK, block_offA);
    k_scanwrite<<<NBLK, 256, 0, stream>>>(hist, block_offA, rs, cur);
    // scan machine blockhist (128*1024)
    k_blocksum<<<NBLK_M, 256, 0, stream>>>(blockhist, partialB);
    k_scanpart<<<1, 256, 0, stream>>>(partialB, NBLK_M, block_offB);
    k_scanwrite<<<NBLK_M, 256, 0, stream>>>(blockhist, block_offB, moff, nullptr);
    k_machrs<<<1, 256, 0, stream>>>(moff, mach_rs, E);
    // fills
    k_fill_op<<<(nprec + E + 255) / 256, 256, 0, stream>>>(prec_e, nprec, comp_e, E, M, cur, bucket_all);
    k_fill_mach<<<NBM, 256, 0, stream>>>(comp_e, E, M, moff, bucket_mach);

    // ---- input embeddings ----
    k_embed<<<(M * HDIM + 255) / 256, 256, 0, stream>>>(op_feat, op_emb_W, op_emb_b, op_emb, M, 6);
    k_embed<<<(NM * HDIM + 255) / 256, 256, 0, stream>>>(m_feat, mach_emb_W, mach_emb_b, mach_emb, NM, 2);

    for (int l = 0; l < 2; ++l) {
        int last = (l == 1);
        const float* Wp = prec_W   + (size_t)l * HDIM * HDIM;
        const float* bp = prec_b   + (size_t)l * HDIM;
        const float* Wc = compat_W + (size_t)l * HDIM * HDIM;
        const float* bc = compat_b + (size_t)l * HDIM;

        hipMemsetAsync(mach_sum, 0, (size_t)NM * HDIM * sizeof(float), stream);

        // both aggregations read OLD op_emb / mach_emb
        k_agg_op<<<(M + 3) / 4, 256, 0, stream>>>(op_emb, mach_emb, rs, bucket_all, A, flags, M);
        k_mach_gather<<<dim3(NM, 4), 256, 0, stream>>>(mach_rs, bucket_mach, op_emb, mach_sum);

        // op update (overwrites op_emb after all reads of it)
        k_gemm_ln<<<(M + BM - 1) / BM, 256, 0, stream>>>(
            A, op_emb, Wp, bp, Wc, bc, flags,
            op_ln_g + (size_t)l * HDIM, op_ln_b + (size_t)l * HDIM,
            last ? out : op_emb, M);

        // machine update (overwrites mach_emb after k_agg_op read it)
        k_mach_update<<<NM, 128, 0, stream>>>(
            mach_emb, mach_sum, mach_rs, Wc, bc,
            mach_ln_g + (size_t)l * HDIM, mach_ln_b + (size_t)l * HDIM,
            last ? (out + (size_t)M * HDIM) : mach_emb);
    }
}

// Round 8
// 821.457 us; speedup vs baseline: 2.4845x; 1.1154x over previous
//
#include <hip/hip_runtime.h>
#include <hip/hip_bf16.h>

#define NUM_OPS   100000
#define NUM_MACH  512
#define HDIM      128
#define P1        100352            // m2o hist offset (98*1024)
#define NHIST     200704            // 196*1024 combined hist size
#define NBLK      196               // hist scan blocks (1024 elems each)
#define NBM       256               // counting-sort blocks for machine buckets
#define MHWORDS   (NUM_MACH * NBM)  // 131072 = 128*1024
#define NBLK_M    128               // blockhist scan blocks

typedef short short8 __attribute__((ext_vector_type(8)));
typedef float floatx4 __attribute__((ext_vector_type(4)));

__device__ __forceinline__ unsigned short f2bf(float f) {
    unsigned u = __float_as_uint(f);
    unsigned r = (u + 0x7FFFu + ((u >> 16) & 1u)) >> 16;   // RNE
    return (unsigned short)r;
}

// ---------------- embedding: out[r,h] = sum_f F[r,f]*W[h,f] + b[h] ----------------
__global__ void k_embed(const float* __restrict__ F,
                        const float* __restrict__ W,
                        const float* __restrict__ b,
                        float* __restrict__ out, int M, int FD) {
    int idx = blockIdx.x * blockDim.x + threadIdx.x;
    if (idx >= M * HDIM) return;
    int r = idx >> 7, h = idx & 127;
    const float* f = F + (size_t)r * FD;
    const float* w = W + (size_t)h * FD;
    float s = b[h];
    for (int i = 0; i < FD; ++i) s += f[i] * w[i];
    out[idx] = s;
}

// ---------------- weight convert: Wb[l][h][0:256] = bf16(Wp[l][h] || Wc[l][h]) ----------------
__global__ void k_wconv(const float* __restrict__ Wp, const float* __restrict__ Wc,
                        unsigned short* __restrict__ Wb) {
    int i = blockIdx.x * blockDim.x + threadIdx.x;
    if (i >= 2 * 128 * 256) return;
    int l = i >> 15, h = (i >> 8) & 127, k = i & 255;
    float v = (k < 128) ? Wp[(size_t)l * 16384 + h * 128 + k]
                        : Wc[(size_t)l * 16384 + h * 128 + (k - 128)];
    Wb[i] = f2bf(v);
}

// ---------------- op-side histogram: prec targets + m2o targets (both op-indexed) ----------------
__global__ void k_hist(const int* __restrict__ prec_e, int nprec,
                       const int* __restrict__ comp_e, int E,
                       int* __restrict__ hist) {
    int i = blockIdx.x * blockDim.x + threadIdx.x;
    if (i >= nprec + E) return;
    if (i < nprec) atomicAdd(&hist[prec_e[nprec + i]], 1);
    else           atomicAdd(&hist[P1 + comp_e[i - nprec]], 1);   // m2o target = op of pair
}

// ---------------- machine counting-sort pass A: per-block LDS histograms ----------------
__global__ __launch_bounds__(256) void k_mhist(const int* __restrict__ comp_e, int E, int M,
                                               int* __restrict__ blockhist) {
    __shared__ int h[NUM_MACH];
    for (int i = threadIdx.x; i < NUM_MACH; i += 256) h[i] = 0;
    __syncthreads();
    int blk = blockIdx.x;
    int ch = (E + NBM - 1) / NBM;
    int e0 = blk * ch, e1 = min(E, e0 + ch);
    for (int e = e0 + threadIdx.x; e < e1; e += 256)
        atomicAdd(&h[comp_e[E + e] - M], 1);
    __syncthreads();
    for (int i = threadIdx.x; i < NUM_MACH; i += 256)
        blockhist[i * NBM + blk] = h[i];
}

// ---------------- scan phase 1: per-block sums (1024 ints / block) ----------------
__global__ __launch_bounds__(256) void k_blocksum(const int* __restrict__ arr, int* __restrict__ partial) {
    __shared__ int sh[256];
    int b = blockIdx.x, t = threadIdx.x;
    int4 v = *(const int4*)(arr + b * 1024 + t * 4);
    sh[t] = v.x + v.y + v.z + v.w;
    __syncthreads();
    for (int o = 128; o; o >>= 1) { if (t < o) sh[t] += sh[t + o]; __syncthreads(); }
    if (!t) partial[b] = sh[0];
}

// ---------------- scan phase 2: exclusive scan of <=256 partials, single block ----------------
__global__ __launch_bounds__(256) void k_scanpart(const int* __restrict__ partial, int n,
                                                  int* __restrict__ block_off) {
    __shared__ int sh[256];
    int t = threadIdx.x;
    int v = (t < n) ? partial[t] : 0;
    sh[t] = v; __syncthreads();
    for (int o = 1; o < 256; o <<= 1) {
        int x = (t >= o) ? sh[t - o] : 0; __syncthreads();
        sh[t] += x; __syncthreads();
    }
    if (t < n) block_off[t] = sh[t] - v;
}

// ---------------- scan phase 3: write exclusive offsets (+ optional cursor copy) ----------------
__global__ __launch_bounds__(256) void k_scanwrite(const int* __restrict__ arr,
                                                   const int* __restrict__ block_off,
                                                   int* __restrict__ rs, int* __restrict__ cur) {
    __shared__ int sh[256];
    int b = blockIdx.x, t = threadIdx.x;
    int base_i = b * 1024 + t * 4;
    int4 v = *(const int4*)(arr + base_i);
    int tsum = v.x + v.y + v.z + v.w;
    sh[t] = tsum; __syncthreads();
    for (int o = 1; o < 256; o <<= 1) {
        int x = (t >= o) ? sh[t - o] : 0; __syncthreads();
        sh[t] += x; __syncthreads();
    }
    int off = block_off[b] + sh[t] - tsum;
    int4 r; r.x = off; r.y = off + v.x; r.z = off + v.x + v.y; r.w = off + v.x + v.y + v.z;
    *(int4*)(rs + base_i) = r;
    if (cur) *(int4*)(cur + base_i) = r;
}

// ---------------- extract machine row starts from scanned blockhist column 0 ----------------
__global__ void k_machrs(const int* __restrict__ moff, int* __restrict__ mach_rs, int E) {
    int t = threadIdx.x;
    for (int m = t; m < NUM_MACH; m += 256) mach_rs[m] = moff[m * NBM];
    if (t == 0) mach_rs[NUM_MACH] = E;
}

// ---------------- op-side bucket fill (atomic cursors; chain ~8) ----------------
__global__ void k_fill_op(const int* __restrict__ prec_e, int nprec,
                          const int* __restrict__ comp_e, int E, int M,
                          int* __restrict__ cur, int* __restrict__ bucket_all) {
    int i = blockIdx.x * blockDim.x + threadIdx.x;
    if (i >= nprec + E) return;
    if (i < nprec) {
        int s = prec_e[i], t = prec_e[nprec + i];
        bucket_all[atomicAdd(&cur[t], 1)] = s;
    } else {
        int e = i - nprec;
        int opi = comp_e[e];
        int m = comp_e[E + e] - M;
        bucket_all[atomicAdd(&cur[P1 + opi], 1)] = m;
    }
}

// ---------------- machine counting-sort pass B: placement via LDS cursors ----------------
__global__ __launch_bounds__(256) void k_fill_mach(const int* __restrict__ comp_e, int E, int M,
                                                   const int* __restrict__ moff,
                                                   int* __restrict__ bucket_mach) {
    __shared__ int cur[NUM_MACH];
    int blk = blockIdx.x;
    for (int i = threadIdx.x; i < NUM_MACH; i += 256) cur[i] = moff[i * NBM + blk];
    __syncthreads();
    int ch = (E + NBM - 1) / NBM;
    int e0 = blk * ch, e1 = min(E, e0 + ch);
    for (int e = e0 + threadIdx.x; e < e1; e += 256) {
        int m = comp_e[E + e] - M;
        int op = comp_e[e];
        int pos = atomicAdd(&cur[m], 1);
        bucket_mach[pos] = op;
    }
}

// ---------------- op aggregation (ILP gathers) -> bf16 A ----------------
__global__ __launch_bounds__(256) void k_agg_op(
    const float* __restrict__ op_emb, const float* __restrict__ mach_emb,
    const int* __restrict__ rs, const int* __restrict__ bucket_all,
    unsigned short* __restrict__ Ab, int* __restrict__ flags, int M) {
    int wave = threadIdx.x >> 6, lane = threadIdx.x & 63;
    int r = blockIdx.x * 4 + wave;
    if (r >= M) return;
    int h = lane * 2;

    float a0 = 0.f, a1 = 0.f;
    int s0 = rs[r], e0 = rs[r + 1];
    for (int base = s0; base < e0; base += 64) {
        int cnt = min(64, e0 - base);
        int idx = (lane < cnt) ? bucket_all[base + lane] : 0;
        for (int j = 0; j < cnt; j += 4) {
            int i0 = __shfl(idx, j);
            int i1 = __shfl(idx, j + 1);
            int i2 = __shfl(idx, j + 2);
            int i3 = __shfl(idx, j + 3);
            float2 v0 = *(const float2*)(op_emb + (size_t)i0 * HDIM + h);
            float2 v1 = *(const float2*)(op_emb + (size_t)i1 * HDIM + h);
            float2 v2 = *(const float2*)(op_emb + (size_t)i2 * HDIM + h);
            float2 v3 = *(const float2*)(op_emb + (size_t)i3 * HDIM + h);
            a0 += v0.x; a1 += v0.y;
            if (j + 1 < cnt) { a0 += v1.x; a1 += v1.y; }
            if (j + 2 < cnt) { a0 += v2.x; a1 += v2.y; }
            if (j + 3 < cnt) { a0 += v3.x; a1 += v3.y; }
        }
    }
    float pinv = 1.f / fmaxf((float)(e0 - s0), 1.f);

    float b0 = 0.f, b1 = 0.f;
    int s1 = rs[P1 + r], e1 = rs[P1 + r + 1];
    for (int base = s1; base < e1; base += 64) {
        int cnt = min(64, e1 - base);
        int idx = (lane < cnt) ? bucket_all[base + lane] : 0;
        for (int j = 0; j < cnt; j += 4) {
            int i0 = __shfl(idx, j);
            int i1 = __shfl(idx, j + 1);
            int i2 = __shfl(idx, j + 2);
            int i3 = __shfl(idx, j + 3);
            float2 v0 = *(const float2*)(mach_emb + (size_t)i0 * HDIM + h);
            float2 v1 = *(const float2*)(mach_emb + (size_t)i1 * HDIM + h);
            float2 v2 = *(const float2*)(mach_emb + (size_t)i2 * HDIM + h);
            float2 v3 = *(const float2*)(mach_emb + (size_t)i3 * HDIM + h);
            b0 += v0.x; b1 += v0.y;
            if (j + 1 < cnt) { b0 += v1.x; b1 += v1.y; }
            if (j + 2 < cnt) { b0 += v2.x; b1 += v2.y; }
            if (j + 3 < cnt) { b0 += v3.x; b1 += v3.y; }
        }
    }
    float cinv = 1.f / fmaxf((float)(e1 - s1), 1.f);

    ushort2 pa, pb;
    pa.x = f2bf(a0 * pinv); pa.y = f2bf(a1 * pinv);
    pb.x = f2bf(b0 * cinv); pb.y = f2bf(b1 * cinv);
    *(ushort2*)(Ab + (size_t)r * 256 + h)       = pa;
    *(ushort2*)(Ab + (size_t)r * 256 + 128 + h) = pb;
    if (lane == 0) flags[r] = (e0 > s0 ? 1 : 0) | (e1 > s1 ? 2 : 0);
}

// ---------------- MFMA GEMM + residual + bias-flags + LayerNorm ----------------
// out[r] = LN(emb[r] + A[r,0:256]@Wb^T + fp*bp + fc*bc)
// A-operand layout: A[m=lane&15][k=quad*8+j]; C/D: row=quad*4+reg, col=lane&15.
__global__ __launch_bounds__(256) void k_gemm_mfma(
    const unsigned short* __restrict__ Ab, const float* __restrict__ emb,
    const unsigned short* __restrict__ Wb,
    const float* __restrict__ bp, const float* __restrict__ bc,
    const int* __restrict__ flags,
    const float* __restrict__ g, const float* __restrict__ bt,
    float* __restrict__ dst, int M) {
    int wave = threadIdx.x >> 6, lane = threadIdx.x & 63;
    int m0 = blockIdx.x * 64 + wave * 16;
    if (m0 >= M) return;
    int quad = lane >> 4, col = lane & 15;

    floatx4 acc[8];
#pragma unroll
    for (int t = 0; t < 8; ++t) acc[t] = (floatx4){0.f, 0.f, 0.f, 0.f};

    const short* Arow  = (const short*)(Ab + (size_t)(m0 + col) * 256);
    const short* Wbase = (const short*)Wb;

#pragma unroll
    for (int ks = 0; ks < 8; ++ks) {
        short8 a = *(const short8*)(Arow + ks * 32 + quad * 8);
#pragma unroll
        for (int t = 0; t < 8; ++t) {
            short8 b = *(const short8*)(Wbase + (size_t)(t * 16 + col) * 256 + ks * 32 + quad * 8);
            acc[t] = __builtin_amdgcn_mfma_f32_16x16x32_bf16(a, b, acc[t], 0, 0, 0);
        }
    }

    float bpv[8], bcv[8], gv[8], btv[8];
#pragma unroll
    for (int t = 0; t < 8; ++t) {
        int c = t * 16 + col;
        bpv[t] = bp[c]; bcv[t] = bc[c]; gv[t] = g[c]; btv[t] = bt[c];
    }
#pragma unroll
    for (int reg = 0; reg < 4; ++reg) {
        int r = m0 + quad * 4 + reg;
        int fl = flags[r];
        float fp = (fl & 1) ? 1.f : 0.f, fc = (fl & 2) ? 1.f : 0.f;
        float x[8]; float s = 0.f, q = 0.f;
#pragma unroll
        for (int t = 0; t < 8; ++t) {
            float v = acc[t][reg] + emb[(size_t)r * HDIM + t * 16 + col] + fp * bpv[t] + fc * bcv[t];
            x[t] = v; s += v; q += v * v;
        }
#pragma unroll
        for (int msk = 1; msk < 16; msk <<= 1) { s += __shfl_xor(s, msk); q += __shfl_xor(q, msk); }
        float mu = s * (1.f / 128.f);
        float rstd = rsqrtf(fmaxf(q * (1.f / 128.f) - mu * mu, 0.f) + 1e-5f);
#pragma unroll
        for (int t = 0; t < 8; ++t)
            dst[(size_t)r * HDIM + t * 16 + col] = (x[t] - mu) * rstd * gv[t] + btv[t];
    }
}

// ---------------- machine gather, ILP version: wave-pair owns 64-edge batch ----------------
__global__ __launch_bounds__(256) void k_mach_gather(
    const int* __restrict__ mach_rs, const int* __restrict__ bucket_mach,
    const float* __restrict__ op_emb, float* __restrict__ mach_sum) {
    int m = blockIdx.x;
    int t = threadIdx.x;
    int wave = t >> 6, lane = t & 63;
    int h = (wave & 1) * 64 + lane;
    int pair = wave >> 1;
    int s0 = mach_rs[m], e0 = mach_rs[m + 1];
    float acc = 0.f;
    for (int base = s0 + (blockIdx.y * 2 + pair) * 64; base < e0; base += gridDim.y * 128) {
        int cnt = min(64, e0 - base);
        int idx = (lane < cnt) ? bucket_mach[base + lane] : 0;
        for (int j = 0; j < cnt; j += 4) {
            int i0 = __shfl(idx, j);
            int i1 = __shfl(idx, j + 1);
            int i2 = __shfl(idx, j + 2);
            int i3 = __shfl(idx, j + 3);
            float v0 = op_emb[(size_t)i0 * HDIM + h];
            float v1 = op_emb[(size_t)i1 * HDIM + h];
            float v2 = op_emb[(size_t)i2 * HDIM + h];
            float v3 = op_emb[(size_t)i3 * HDIM + h];
            acc += v0;
            if (j + 1 < cnt) acc += v1;
            if (j + 2 < cnt) acc += v2;
            if (j + 3 < cnt) acc += v3;
        }
    }
    atomicAdd(&mach_sum[m * HDIM + h], acc);
}

// ---------------- machine update: mean -> @Wc^T + bc -> +emb -> LN ----------------
__global__ __launch_bounds__(128) void k_mach_update(
    const float* __restrict__ mach_emb, const float* __restrict__ mach_sum,
    const int* __restrict__ mach_rs,
    const float* __restrict__ Wc, const float* __restrict__ bc,
    const float* __restrict__ g, const float* __restrict__ bt,
    float* __restrict__ dst) {
    __shared__ float row[HDIM];
    __shared__ float red[4];
    int m = blockIdx.x, t = threadIdx.x;
    int cnt = mach_rs[m + 1] - mach_rs[m];
    float sc = (cnt > 0) ? 1.f / (float)cnt : 0.f;
    row[t] = mach_sum[m * HDIM + t] * sc;
    __syncthreads();
    float dot = bc[t];
    const float* w = Wc + (size_t)t * HDIM;
#pragma unroll 8
    for (int k = 0; k < HDIM; ++k) dot += row[k] * w[k];
    float x = mach_emb[m * HDIM + t] + ((cnt > 0) ? dot : 0.f);
    float s = x, q = x * x;
#pragma unroll
    for (int o = 32; o; o >>= 1) { s += __shfl_xor(s, o); q += __shfl_xor(q, o); }
    int wv = t >> 6;
    if ((t & 63) == 0) { red[wv * 2] = s; red[wv * 2 + 1] = q; }
    __syncthreads();
    s = red[0] + red[2]; q = red[1] + red[3];
    float mu = s * (1.f / 128.f);
    float rstd = rsqrtf(fmaxf(q * (1.f / 128.f) - mu * mu, 0.f) + 1e-5f);
    dst[m * HDIM + t] = (x - mu) * rstd * g[t] + bt[t];
}

extern "C" void kernel_launch(void* const* d_in, const int* in_sizes, int n_in,
                              void* d_out, int out_size, void* d_ws, size_t ws_size,
                              hipStream_t stream) {
    const float* op_feat    = (const float*)d_in[0];
    const float* m_feat     = (const float*)d_in[1];
    const int*   prec_e     = (const int*)d_in[2];
    const int*   comp_e     = (const int*)d_in[3];
    const float* op_emb_W   = (const float*)d_in[4];
    const float* op_emb_b   = (const float*)d_in[5];
    const float* mach_emb_W = (const float*)d_in[6];
    const float* mach_emb_b = (const float*)d_in[7];
    const float* prec_W     = (const float*)d_in[8];
    const float* prec_b     = (const float*)d_in[9];
    const float* compat_W   = (const float*)d_in[10];
    const float* compat_b   = (const float*)d_in[11];
    const float* op_ln_g    = (const float*)d_in[12];
    const float* op_ln_b    = (const float*)d_in[13];
    const float* mach_ln_g  = (const float*)d_in[14];
    const float* mach_ln_b  = (const float*)d_in[15];
    float* out = (float*)d_out;

    const int M = NUM_OPS, NM = NUM_MACH;
    const int nprec = in_sizes[2] / 2;
    const int ncomp = in_sizes[3] / 2;
    const int E = ncomp / 2;   // bidirectional pairs: first half o2m, second half m2o (mirror)

    float* ws = (float*)d_ws;
    size_t o = 0;
    float* op_emb   = ws + o; o += (size_t)M * HDIM;    // 51 MB
    unsigned short* Ab = (unsigned short*)(ws + o); o += (size_t)M * 128;  // 51 MB bf16 [M][256]
    unsigned short* Wb = (unsigned short*)(ws + o); o += 32768;            // 2 layers x [128][256] bf16
    float* mach_emb = ws + o; o += (size_t)NM * HDIM;
    float* mach_sum = ws + o; o += (size_t)NM * HDIM;
    int* ip = (int*)(ws + o);
    size_t io = 0;
    int* hist      = ip + io; io += NHIST;
    int* rs        = ip + io; io += NHIST;
    int* cur       = ip + io; io += NHIST;
    int* blockhist = ip + io; io += MHWORDS;
    int* moff      = ip + io; io += MHWORDS;
    int* mach_rs   = ip + io; io += NM + 8;
    int* partialA  = ip + io; io += 256;
    int* block_offA= ip + io; io += 256;
    int* partialB  = ip + io; io += 256;
    int* block_offB= ip + io; io += 256;
    int* flags     = ip + io; io += M;
    int* bucket_all  = ip + io; io += (size_t)nprec + E;
    int* bucket_mach = ip + io; io += (size_t)E;

    // ---- CSR build ----
    hipMemsetAsync(hist, 0, (size_t)NHIST * sizeof(int), stream);
    k_hist<<<(nprec + E + 255) / 256, 256, 0, stream>>>(prec_e, nprec, comp_e, E, hist);
    k_mhist<<<NBM, 256, 0, stream>>>(comp_e, E, M, blockhist);
    k_blocksum<<<NBLK, 256, 0, stream>>>(hist, partialA);
    k_scanpart<<<1, 256, 0, stream>>>(partialA, NBLK, block_offA);
    k_scanwrite<<<NBLK, 256, 0, stream>>>(hist, block_offA, rs, cur);
    k_blocksum<<<NBLK_M, 256, 0, stream>>>(blockhist, partialB);
    k_scanpart<<<1, 256, 0, stream>>>(partialB, NBLK_M, block_offB);
    k_scanwrite<<<NBLK_M, 256, 0, stream>>>(blockhist, block_offB, moff, nullptr);
    k_machrs<<<1, 256, 0, stream>>>(moff, mach_rs, E);
    k_fill_op<<<(nprec + E + 255) / 256, 256, 0, stream>>>(prec_e, nprec, comp_e, E, M, cur, bucket_all);
    k_fill_mach<<<NBM, 256, 0, stream>>>(comp_e, E, M, moff, bucket_mach);

    // ---- input embeddings + weight conversion ----
    k_embed<<<(M * HDIM + 255) / 256, 256, 0, stream>>>(op_feat, op_emb_W, op_emb_b, op_emb, M, 6);
    k_embed<<<(NM * HDIM + 255) / 256, 256, 0, stream>>>(m_feat, mach_emb_W, mach_emb_b, mach_emb, NM, 2);
    k_wconv<<<(2 * 128 * 256 + 255) / 256, 256, 0, stream>>>(prec_W, compat_W, Wb);

    for (int l = 0; l < 2; ++l) {
        int last = (l == 1);
        const float* bpl = prec_b   + (size_t)l * HDIM;
        const float* Wc  = compat_W + (size_t)l * HDIM * HDIM;
        const float* bcl = compat_b + (size_t)l * HDIM;

        hipMemsetAsync(mach_sum, 0, (size_t)NM * HDIM * sizeof(float), stream);

        // both aggregations read OLD op_emb / mach_emb
        k_agg_op<<<(M + 3) / 4, 256, 0, stream>>>(op_emb, mach_emb, rs, bucket_all, Ab, flags, M);
        k_mach_gather<<<dim3(NM, 4), 256, 0, stream>>>(mach_rs, bucket_mach, op_emb, mach_sum);

        // op update (overwrites op_emb after all reads of it)
        k_gemm_mfma<<<(M + 63) / 64, 256, 0, stream>>>(
            Ab, op_emb, Wb + (size_t)l * 128 * 256, bpl, bcl, flags,
            op_ln_g + (size_t)l * HDIM, op_ln_b + (size_t)l * HDIM,
            last ? out : op_emb, M);

        // machine update (overwrites mach_emb after k_agg_op read it)
        k_mach_update<<<NM, 128, 0, stream>>>(
            mach_emb, mach_sum, mach_rs, Wc, bcl,
            mach_ln_g + (size_t)l * HDIM, mach_ln_b + (size_t)l * HDIM,
            last ? (out + (size_t)M * HDIM) : mach_emb);
    }
}